// Round 15
// baseline (966.117 us; speedup 1.0000x reference)
//
#include <hip/hip_runtime.h>

#define LAYERS 8
#define DIM 512
#define FFD 2048
#define NTOK 6272   // 32 * 196
#define NSEQ 196
#define BATCH 32
#define NHEAD 16
#define HD 32
#define NP 224      // padded seq for attention tiles

typedef unsigned short u16;
typedef __bf16 bf16x8 __attribute__((ext_vector_type(8)));
typedef float f32x4 __attribute__((ext_vector_type(4)));
typedef unsigned short u16x8 __attribute__((ext_vector_type(8)));

__device__ __forceinline__ u16 f2bf(float f) {
    unsigned u = __float_as_uint(f);
    u += 0x7FFF + ((u >> 16) & 1);   // round-to-nearest-even
    return (u16)(u >> 16);
}
__device__ __forceinline__ float bf2f(u16 u) {
    return __uint_as_float((unsigned)u << 16);
}

typedef __attribute__((address_space(1))) void gvoid_t;
typedef __attribute__((address_space(3))) void lvoid_t;
__device__ __forceinline__ void gload_lds16(const void* g, void* l) {
    __builtin_amdgcn_global_load_lds((gvoid_t*)g, (lvoid_t*)l, 16, 0, 0);
}

// ---------------- weight transpose + bf16 convert ----------------
// 4-in-1 for the DxD weights: z = sel*LAYERS + layer, sel in {q,k,v,o}
__global__ __launch_bounds__(256) void transpose_w4(const float* __restrict__ Wq,
                                                    const float* __restrict__ Wk,
                                                    const float* __restrict__ Wv,
                                                    const float* __restrict__ Wo,
                                                    u16* __restrict__ out) {
    __shared__ float t[32][33];
    int z = blockIdx.z;
    int sel = z >> 3, l = z & 7;
    const float* in = (sel == 0) ? Wq : (sel == 1) ? Wk : (sel == 2) ? Wv : Wo;
    size_t ibase = (size_t)l * DIM * DIM;
    size_t obase = (size_t)z * DIM * DIM;
    int n0 = blockIdx.x * 32, k0 = blockIdx.y * 32;
    int tx = threadIdx.x, ty = threadIdx.y;
#pragma unroll
    for (int i = 0; i < 4; ++i)
        t[ty + i * 8][tx] = in[ibase + (size_t)(k0 + ty + i * 8) * DIM + n0 + tx];
    __syncthreads();
#pragma unroll
    for (int i = 0; i < 4; ++i)
        out[obase + (size_t)(n0 + ty + i * 8) * DIM + k0 + tx] = f2bf(t[tx][ty + i * 8]);
}

__global__ __launch_bounds__(256) void transpose_w(const float* __restrict__ in,
                                                   u16* __restrict__ out, int K, int N) {
    __shared__ float t[32][33];
    size_t base = (size_t)blockIdx.z * K * N;
    int n0 = blockIdx.x * 32, k0 = blockIdx.y * 32;
    int tx = threadIdx.x, ty = threadIdx.y;
#pragma unroll
    for (int i = 0; i < 4; ++i)
        t[ty + i * 8][tx] = in[base + (size_t)(k0 + ty + i * 8) * N + n0 + tx];
    __syncthreads();
#pragma unroll
    for (int i = 0; i < 4; ++i)
        out[base + (size_t)(n0 + ty + i * 8) * K + k0 + tx] = f2bf(t[tx][ty + i * 8]);
}

__global__ void pack3_bias(const float* __restrict__ a, const float* __restrict__ b,
                           const float* __restrict__ c, float* __restrict__ o, int n) {
    int i = blockIdx.x * 256 + threadIdx.x;
    if (i < n) { o[i] = a[i]; o[n + i] = b[i]; o[2 * n + i] = c[i]; }
}

// ---------------- gather/unshuffle + pos_emb ----------------
__global__ __launch_bounds__(128) void gather_pos(const float* __restrict__ xenc,
                                                  const int* __restrict__ idx,
                                                  const float* __restrict__ mtok,
                                                  const float* __restrict__ pos,
                                                  float* __restrict__ x, u16* __restrict__ xb) {
    int token = blockIdx.x;
    int b = token / NSEQ, t = token - b * NSEQ;
    int id = idx[token];
    const float* src = (id < 49) ? (xenc + ((size_t)b * 50 + id + 1) * DIM) : mtok;
    int d = threadIdx.x * 4;
    float4 s = *(const float4*)(src + d);
    float4 p = *(const float4*)(pos + (size_t)t * DIM + d);
    float4 r;
    r.x = s.x + p.x; r.y = s.y + p.y; r.z = s.z + p.z; r.w = s.w + p.w;
    *(float4*)(x + (size_t)token * DIM + d) = r;
    ushort4 rb;
    rb.x = f2bf(r.x); rb.y = f2bf(r.y); rb.z = f2bf(r.z); rb.w = f2bf(r.w);
    *(ushort4*)(xb + (size_t)token * DIM + d) = rb;
}

// ---------------- 4-wave 128x128 bf16 MFMA GEMM, BK=64, dbuf + counted vmcnt ----------------
// B^T input (Wt[N][K]); grid.z = slab (weight slab or K-slice)
// EPI 1: relu(A@B+bias)->bf16   EPI 3: A@B+bias->bf16   EPI 4: A@B->bf16 partial
// XOR swizzle ((row&7)<<4) via inverse-swizzled GLOBAL source offset (LDS dest
// linear, required by global_load_lds) + swizzled fragment reads.
// Pipeline (T3/T4): STAGE(next) then s_waitcnt vmcnt(8) — waits only for the
// CURRENT tile's 8 loads, never draining the just-issued prefetch.
// B stays LDS-staged: rounds 12/13 proved direct global->VGPR B either exposes
// L2 latency (r12) or thrashes cache (r13, FETCH 26->67MB).
// Epilogue: C bounced through LDS -> 8x u16x8 coalesced stores per thread.
// Cross-thread LDS exchange REQUIRES __syncthreads (round-10 race).
template<int EPI>
__global__ __launch_bounds__(256) void gemm4(
    const u16* __restrict__ A, int lda, long long zsA,
    const u16* __restrict__ Bt, int ldb, long long zsB,
    const float* __restrict__ bias, long long zsBias,
    u16* __restrict__ outB, long long zsOut,
    int N, int K) {
    __shared__ u16 smem[32768];        // 64KB: As dbuf [0..16383], Bs dbuf [16384..32767]
    int tid = threadIdx.x;
    int lane = tid & 63, wid = tid >> 6;
    int z = blockIdx.z;
    const u16* Az = A + (size_t)z * zsA;
    const u16* Bz = Bt + (size_t)z * zsB;
    int m0 = blockIdx.y * 128, n0 = blockIdx.x * 128;
    int l16 = lane & 15, kq = lane >> 4;
    int wm = (wid >> 1) * 64, wn = (wid & 1) * 64;

    f32x4 acc[4][4];
    f32x4 zero = {0.f, 0.f, 0.f, 0.f};
#pragma unroll
    for (int a = 0; a < 4; ++a)
#pragma unroll
        for (int b = 0; b < 4; ++b) acc[a][b] = zero;

#define STAGE(buf, kk)                                                             \
    {                                                                              \
        u16* asb_ = smem + (buf) * 8192;                                           \
        u16* bsb_ = smem + 16384 + (buf) * 8192;                                   \
        _Pragma("unroll")                                                          \
        for (int i_ = 0; i_ < 4; ++i_) {                                           \
            int c_ = i_ * 256 + tid;               /* 16B chunk id 0..1023 */      \
            int row_ = c_ >> 3;                    /* 128B (64 bf16) rows */       \
            int kof_ = ((c_ & 7) * 16) ^ ((row_ & 7) << 4);                        \
            gload_lds16((const char*)Az + ((size_t)(m0 + row_) * lda + (kk)) * 2 + kof_, \
                        (char*)asb_ + (size_t)c_ * 16);                            \
            gload_lds16((const char*)Bz + ((size_t)(n0 + row_) * ldb + (kk)) * 2 + kof_, \
                        (char*)bsb_ + (size_t)c_ * 16);                            \
        }                                                                          \
    }

    int nk = K >> 6;
    STAGE(0, 0);                       // 8 vmem ops in flight (tile 0)
    for (int kt = 0; kt < nk; ++kt) {
        int cur = kt & 1;
        if (kt + 1 < nk) {
            STAGE(cur ^ 1, (kt + 1) << 6);                     // +8 (tile kt+1)
            asm volatile("s_waitcnt vmcnt(8)" ::: "memory");   // tile kt landed
        } else {
            asm volatile("s_waitcnt vmcnt(0)" ::: "memory");   // final drain
        }
        __builtin_amdgcn_s_barrier();
        const char* Ac = (const char*)(smem + cur * 8192);
        const char* Bc = (const char*)(smem + 16384 + cur * 8192);
#pragma unroll
        for (int kh = 0; kh < 2; ++kh) {
            bf16x8 af[4], bfr[4];
#pragma unroll
            for (int mr = 0; mr < 4; ++mr) {
                int row = wm + mr * 16 + l16;
                int cb = (kh * 64 + kq * 16) ^ ((row & 7) << 4);
                af[mr] = *(const bf16x8*)(Ac + row * 128 + cb);
            }
#pragma unroll
            for (int nc = 0; nc < 4; ++nc) {
                int row = wn + nc * 16 + l16;
                int cb = (kh * 64 + kq * 16) ^ ((row & 7) << 4);
                bfr[nc] = *(const bf16x8*)(Bc + row * 128 + cb);
            }
#pragma unroll
            for (int mr = 0; mr < 4; ++mr)
#pragma unroll
                for (int nc = 0; nc < 4; ++nc)
                    acc[mr][nc] = __builtin_amdgcn_mfma_f32_16x16x32_bf16(af[mr], bfr[nc],
                                                                          acc[mr][nc], 0, 0, 0);
        }
        __builtin_amdgcn_s_barrier();  // all reads of buf cur done before it is re-staged
    }
#undef STAGE

    // ---- epilogue: bounce C tile through LDS (dead after K-loop) ----
    __syncthreads();                   // full drain: safe to repurpose smem
    const float* biasz = (EPI != 4) ? bias + (size_t)z * zsBias : nullptr;
    const int CLD = 136;               // padded u16 row stride (272B)
    u16* Cs = smem;                    // 128*136 = 17408 u16 <= 32768
#pragma unroll
    for (int mr = 0; mr < 4; ++mr)
#pragma unroll
        for (int nc = 0; nc < 4; ++nc)
#pragma unroll
            for (int i = 0; i < 4; ++i) {
                int rl = wm + mr * 16 + kq * 4 + i;   // row = (lane>>4)*4 + reg
                int cl = wn + nc * 16 + l16;          // col = lane&15
                float v = acc[mr][nc][i];
                if (EPI == 1) { v += biasz[n0 + cl]; v = v > 0.f ? v : 0.f; }
                else if (EPI == 3) { v += biasz[n0 + cl]; }
                Cs[rl * CLD + cl] = f2bf(v);
            }
    __syncthreads();                   // lgkmcnt(0) drain + barrier: writes visible
#pragma unroll
    for (int k = 0; k < 8; ++k) {
        int g = k * 256 + tid;                        // 2048 chunks of 16B
        int r = g >> 4, ch = g & 15;
        u16x8 val = *(const u16x8*)&Cs[r * CLD + ch * 8];
        *(u16x8*)&outB[(size_t)z * zsOut + (size_t)(m0 + r) * N + n0 + ch * 8] = val;
    }
}

// ---------------- fused split-K reduce (NS bf16 partial slabs) + bias + residual + LN ----------------
template<int NS>
__global__ __launch_bounds__(256) void red_ln(const u16* __restrict__ p0, long long ps,
                                              const float* __restrict__ bias,
                                              const float* __restrict__ gg,
                                              const float* __restrict__ bb,
                                              float* __restrict__ x, u16* __restrict__ xb) {
    int t = blockIdx.x * 4 + (threadIdx.x >> 6);
    int lane = threadIdx.x & 63;
    size_t base = (size_t)t * DIM;
    int c0 = lane * 8;
    float v[8];
    {
        u16x8 pa = *(const u16x8*)(p0 + base + c0);
#pragma unroll
        for (int i = 0; i < 8; ++i) v[i] = bf2f(pa[i]);
    }
#pragma unroll
    for (int s2i = 1; s2i < NS; ++s2i) {
        u16x8 pb = *(const u16x8*)(p0 + (size_t)s2i * ps + base + c0);
#pragma unroll
        for (int i = 0; i < 8; ++i) v[i] += bf2f(pb[i]);
    }
    float4 xa = *(const float4*)(x + base + c0);
    float4 xc = *(const float4*)(x + base + c0 + 4);
    float4 ba = *(const float4*)(bias + c0);
    float4 bc = *(const float4*)(bias + c0 + 4);
    float xs[8] = {xa.x, xa.y, xa.z, xa.w, xc.x, xc.y, xc.z, xc.w};
    float bs[8] = {ba.x, ba.y, ba.z, ba.w, bc.x, bc.y, bc.z, bc.w};
    float s = 0.f, s2 = 0.f;
#pragma unroll
    for (int i = 0; i < 8; ++i) {
        v[i] += bs[i] + xs[i];
        s += v[i]; s2 += v[i] * v[i];
    }
#pragma unroll
    for (int off = 32; off; off >>= 1) { s += __shfl_xor(s, off); s2 += __shfl_xor(s2, off); }
    float m = s * (1.f / 512.f);
    float var = s2 * (1.f / 512.f) - m * m;
    float rs = rsqrtf(var + 1e-5f);
    float4 ga = *(const float4*)(gg + c0);
    float4 gc = *(const float4*)(gg + c0 + 4);
    float4 b0 = *(const float4*)(bb + c0);
    float4 b1 = *(const float4*)(bb + c0 + 4);
    float gs[8] = {ga.x, ga.y, ga.z, ga.w, gc.x, gc.y, gc.z, gc.w};
    float os[8] = {b0.x, b0.y, b0.z, b0.w, b1.x, b1.y, b1.z, b1.w};
    float o[8];
    u16x8 ob16;
#pragma unroll
    for (int i = 0; i < 8; ++i) {
        o[i] = (v[i] - m) * rs * gs[i] + os[i];
        ob16[i] = f2bf(o[i]);
    }
    float4 o0 = {o[0], o[1], o[2], o[3]};
    float4 o1 = {o[4], o[5], o[6], o[7]};
    *(float4*)(x + base + c0) = o0;
    *(float4*)(x + base + c0 + 4) = o1;
    *(u16x8*)(xb + base + c0) = ob16;
}

// ---------------- MFMA flash attention, 2 blocks per (b,h), 4 waves each ----------------
// T5: s_setprio(1) around MFMA clusters — blocks are independent (no lockstep
// barrier in the panel loop), the regime where m191 measured +4-7%. NOT applied
// to gemm4 (m190: null/negative on barrier-locked GEMM).
// ct=13 tile (cols 208..223) is pure pad: never computed, zeros written to Ps.
__global__ __launch_bounds__(256) void attn_mfma(const u16* __restrict__ qkvb,
                                                 u16* __restrict__ ob) {
    __shared__ u16 Ks[NP * 32];            // [224][32] row-major
    __shared__ u16 VTs[32 * 232];          // [32][232] V transposed
    __shared__ u16 Ps[4][16 * 128];        // per-wave P panel, 256B rows
    int bh = blockIdx.x >> 1, half = blockIdx.x & 1;
    int b = bh >> 4, h = bh & 15;
    int tid = threadIdx.x, lane = tid & 63, wid = tid >> 6;
    int l16 = lane & 15, kq = lane >> 4;
    const size_t MS = (size_t)NTOK * DIM;
    const u16* qg = qkvb + ((size_t)b * NSEQ) * DIM + h * HD;
    const u16* kg = qg + MS;
    const u16* vg = qg + 2 * MS;

    for (int c = tid; c < 784; c += 256) {
        int row = c >> 2, ch = c & 3;
        gload_lds16(kg + (size_t)row * DIM + ch * 8, (char*)Ks + c * 16);
    }
    for (int i = tid; i < 448; i += 256) ((unsigned*)(Ks + 196 * 32))[i] = 0;
    for (int i = tid; i < 1568; i += 256) {
        int j = i >> 3, d0 = (i & 7) * 4;
        ushort4 vv = *(const ushort4*)(vg + (size_t)j * DIM + d0);
        VTs[(d0 + 0) * 232 + j] = vv.x;
        VTs[(d0 + 1) * 232 + j] = vv.y;
        VTs[(d0 + 2) * 232 + j] = vv.z;
        VTs[(d0 + 3) * 232 + j] = vv.w;
    }
    for (int i = tid; i < 1024; i += 256) {
        int d = i >> 5, j = 196 + (i & 31);
        VTs[d * 232 + j] = 0;
    }
    __syncthreads();

    const float scale = 0.17677669529663687f;   // 1/sqrt(32)
    char* psb = (char*)&Ps[wid][0];
    int pend = half ? 13 : 7;

    for (int p = half * 7 + wid; p < pend; p += 4) {
        int r0 = p * 16;
        int qrow = r0 + l16; if (qrow > 195) qrow = 195;
        bf16x8 qf = *(const bf16x8*)(qg + (size_t)qrow * DIM + kq * 8);

        f32x4 z4 = {0.f, 0.f, 0.f, 0.f};
        f32x4 s[13];                    // ct=13 (cols 208..223) is all-pad: skipped
        __builtin_amdgcn_s_setprio(1);
#pragma unroll
        for (int ct = 0; ct < 13; ++ct) {
            bf16x8 kf = *(const bf16x8*)&Ks[(ct * 16 + l16) * 32 + kq * 8];
            s[ct] = __builtin_amdgcn_mfma_f32_16x16x32_bf16(qf, kf, z4, 0, 0, 0);
        }
        __builtin_amdgcn_s_setprio(0);
        bool v12 = (l16 < 4);   // tile 12 cols 192..207 valid iff l16<4
        float mx[4], sum[4], inv[4];
#pragma unroll
        for (int i = 0; i < 4; ++i) {
            float m = -1e30f;
#pragma unroll
            for (int ct = 0; ct < 12; ++ct) m = fmaxf(m, s[ct][i]);
            if (v12) m = fmaxf(m, s[12][i]);
            mx[i] = m * scale;
        }
#pragma unroll
        for (int off = 8; off; off >>= 1)
#pragma unroll
            for (int i = 0; i < 4; ++i) mx[i] = fmaxf(mx[i], __shfl_xor(mx[i], off));
#pragma unroll
        for (int i = 0; i < 4; ++i) sum[i] = 0.f;
#pragma unroll
        for (int ct = 0; ct < 13; ++ct)
#pragma unroll
            for (int i = 0; i < 4; ++i) {
                bool valid = (ct < 12) || (ct == 12 && v12);
                float e = valid ? __expf(s[ct][i] * scale - mx[i]) : 0.f;
                s[ct][i] = e;
                sum[i] += e;
            }
#pragma unroll
        for (int off = 8; off; off >>= 1)
#pragma unroll
            for (int i = 0; i < 4; ++i) sum[i] += __shfl_xor(sum[i], off);
#pragma unroll
        for (int i = 0; i < 4; ++i) inv[i] = 1.f / sum[i];

        f32x4 o0 = {0.f, 0.f, 0.f, 0.f}, o1 = {0.f, 0.f, 0.f, 0.f};
        // phase A: col tiles 0..7 -> Ps; PV k-tiles 0..3
#pragma unroll
        for (int ct = 0; ct < 8; ++ct)
#pragma unroll
            for (int i = 0; i < 4; ++i) {
                int rl = kq * 4 + i;
                int byte = rl * 256 + (((ct * 16 + l16) * 2) ^ ((rl & 7) << 4));
                *(u16*)(psb + byte) = f2bf(s[ct][i]);
            }
        __builtin_amdgcn_s_setprio(1);
#pragma unroll
        for (int kt = 0; kt < 4; ++kt) {
            int K2 = (kt * 64 + kq * 16) ^ ((l16 & 7) << 4);
            bf16x8 pa = *(const bf16x8*)(psb + l16 * 256 + K2);
            bf16x8 va = *(const bf16x8*)&VTs[l16 * 232 + kt * 32 + kq * 8];
            bf16x8 vb = *(const bf16x8*)&VTs[(16 + l16) * 232 + kt * 32 + kq * 8];
            o0 = __builtin_amdgcn_mfma_f32_16x16x32_bf16(pa, va, o0, 0, 0, 0);
            o1 = __builtin_amdgcn_mfma_f32_16x16x32_bf16(pa, vb, o1, 0, 0, 0);
        }
        __builtin_amdgcn_s_setprio(0);
        // phase B: col tiles 8..12 -> Ps (reused); tile 13 slot = zeros; PV k-tiles 4..6
#pragma unroll
        for (int ct = 8; ct < 14; ++ct)
#pragma unroll
            for (int i = 0; i < 4; ++i) {
                int rl = kq * 4 + i;
                int byte = rl * 256 + ((((ct - 8) * 16 + l16) * 2) ^ ((rl & 7) << 4));
                *(u16*)(psb + byte) = (ct < 13) ? f2bf(s[ct][i]) : (u16)0;
            }
        __builtin_amdgcn_s_setprio(1);
#pragma unroll
        for (int kt = 4; kt < 7; ++kt) {
            int K2 = ((kt - 4) * 64 + kq * 16) ^ ((l16 & 7) << 4);
            bf16x8 pa = *(const bf16x8*)(psb + l16 * 256 + K2);
            bf16x8 va = *(const bf16x8*)&VTs[l16 * 232 + kt * 32 + kq * 8];
            bf16x8 vb = *(const bf16x8*)&VTs[(16 + l16) * 232 + kt * 32 + kq * 8];
            o0 = __builtin_amdgcn_mfma_f32_16x16x32_bf16(pa, va, o0, 0, 0, 0);
            o1 = __builtin_amdgcn_mfma_f32_16x16x32_bf16(pa, vb, o1, 0, 0, 0);
        }
        __builtin_amdgcn_s_setprio(0);
#pragma unroll
        for (int i = 0; i < 4; ++i) {
            int row = r0 + kq * 4 + i;
            if (row < NSEQ) {
                size_t rb = ((size_t)b * NSEQ + row) * DIM + h * HD;
                ob[rb + l16] = f2bf(o0[i] * inv[i]);
                ob[rb + 16 + l16] = f2bf(o1[i] * inv[i]);
            }
        }
    }
}

// ---------------- final LayerNorm, one wave per token ----------------
__global__ __launch_bounds__(256) void ln_final(const float* __restrict__ y,
                                                const float* __restrict__ gg,
                                                const float* __restrict__ bb,
                                                float* __restrict__ xout) {
    int t = blockIdx.x * 4 + (threadIdx.x >> 6);
    int lane = threadIdx.x & 63;
    const float* row = y + (size_t)t * DIM;
    float4 a = *(const float4*)(row + lane * 4);
    float4 c = *(const float4*)(row + 256 + lane * 4);
    float s = a.x + a.y + a.z + a.w + c.x + c.y + c.z + c.w;
    float s2 = a.x * a.x + a.y * a.y + a.z * a.z + a.w * a.w
             + c.x * c.x + c.y * c.y + c.z * c.z + c.w * c.w;
#pragma unroll
    for (int off = 32; off; off >>= 1) { s += __shfl_xor(s, off); s2 += __shfl_xor(s2, off); }
    float m = s * (1.f / 512.f);
    float var = s2 * (1.f / 512.f) - m * m;
    float rs = rsqrtf(var + 1e-5f);
    float4 g0 = *(const float4*)(gg + lane * 4);
    float4 g1 = *(const float4*)(gg + 256 + lane * 4);
    float4 b0 = *(const float4*)(bb + lane * 4);
    float4 b1 = *(const float4*)(bb + 256 + lane * 4);
    float4 o0, o1;
    o0.x = (a.x - m) * rs * g0.x + b0.x;
    o0.y = (a.y - m) * rs * g0.y + b0.y;
    o0.z = (a.z - m) * rs * g0.z + b0.z;
    o0.w = (a.w - m) * rs * g0.w + b0.w;
    o1.x = (c.x - m) * rs * g1.x + b1.x;
    o1.y = (c.y - m) * rs * g1.y + b1.y;
    o1.z = (c.z - m) * rs * g1.z + b1.z;
    o1.w = (c.w - m) * rs * g1.w + b1.w;
    *(float4*)(xout + (size_t)t * DIM + lane * 4) = o0;
    *(float4*)(xout + (size_t)t * DIM + 256 + lane * 4) = o1;
}

extern "C" void kernel_launch(void* const* d_in, const int* in_sizes, int n_in,
                              void* d_out, int out_size, void* d_ws, size_t ws_size,
                              hipStream_t stream) {
    const float* xenc = (const float*)d_in[0];
    const int*   idxr = (const int*)d_in[1];
    const float* mtok = (const float*)d_in[2];
    const float* pos  = (const float*)d_in[3];
    const float* Wq = (const float*)d_in[4];  const float* bq = (const float*)d_in[5];
    const float* Wk = (const float*)d_in[6];  const float* bk = (const float*)d_in[7];
    const float* Wv = (const float*)d_in[8];  const float* bv = (const float*)d_in[9];
    const float* Wo = (const float*)d_in[10]; const float* bo = (const float*)d_in[11];
    const float* ln1g = (const float*)d_in[12]; const float* ln1b = (const float*)d_in[13];
    const float* W1 = (const float*)d_in[14]; const float* b1 = (const float*)d_in[15];
    const float* W2 = (const float*)d_in[16]; const float* b2 = (const float*)d_in[17];
    const float* ln2g = (const float*)d_in[18]; const float* ln2b = (const float*)d_in[19];
    const float* lnfg = (const float*)d_in[20]; const float* lnfb = (const float*)d_in[21];

    // ---- workspace carve ----
    char* w = (char*)d_ws;
    u16* WTqkvo = (u16*)w; w += (size_t)4 * LAYERS * DIM * DIM * 2;     // bf16 W^T (q,k,v,o)
    u16* WT1    = (u16*)w; w += (size_t)LAYERS * DIM * FFD * 2;         // [8][2048][512]
    u16* WT2    = (u16*)w; w += (size_t)LAYERS * FFD * DIM * 2;         // [8][512][2048]
    float* bqkv = (float*)w; w += (size_t)3 * LAYERS * DIM * 4;         // [3][8][512]
    float* x    = (float*)w; w += (size_t)NTOK * DIM * 4;               // fp32 residual stream
    u16*   xb   = (u16*)w;  w += (size_t)NTOK * DIM * 2;                // bf16 copy of x
    u16*   qkvb = (u16*)w;  w += (size_t)3 * NTOK * DIM * 2;            // q,k,v bf16
    u16*   ob   = (u16*)w;  w += (size_t)NTOK * DIM * 2;                // attention out bf16
    u16*   hb   = (u16*)w;  w += (size_t)NTOK * FFD * 2;                // FF hidden bf16
    size_t need = (size_t)(w - (char*)d_ws);
    if (ws_size < need) return;

    // bf16 split-K partial slabs (2 x ND u16), aliased into qkvb (dead after attn / during FF2)
    u16* pp = qkvb;
    const long long ND = (long long)NTOK * DIM;

    const size_t WL = (size_t)DIM * DIM;

    // ---- weight prep ----
    transpose_w4<<<dim3(DIM / 32, DIM / 32, 4 * LAYERS), dim3(32, 8), 0, stream>>>(Wq, Wk, Wv, Wo, WTqkvo);
    transpose_w<<<dim3(FFD / 32, DIM / 32, LAYERS), dim3(32, 8), 0, stream>>>(W1, WT1, DIM, FFD);
    transpose_w<<<dim3(DIM / 32, FFD / 32, LAYERS), dim3(32, 8), 0, stream>>>(W2, WT2, FFD, DIM);
    pack3_bias<<<(LAYERS * DIM + 255) / 256, 256, 0, stream>>>(bq, bk, bv, bqkv, LAYERS * DIM);

    // ---- embed ----
    gather_pos<<<NTOK, 128, 0, stream>>>(xenc, idxr, mtok, pos, x, xb);

    for (int l = 0; l < LAYERS; ++l) {
        // QKV -> bf16 (z = weight slab 0..2)
        gemm4<3><<<dim3(4, 49, 3), 256, 0, stream>>>(
            xb, DIM, 0, WTqkvo + l * WL, DIM, (long long)LAYERS * WL,
            bqkv + l * DIM, (long long)LAYERS * DIM,
            qkvb, ND, DIM, DIM);
        // MFMA attention (2 blocks per (b,h))
        attn_mfma<<<BATCH * NHEAD * 2, 256, 0, stream>>>(qkvb, ob);
        // out projection, split-K=2 (z = K-slice), bf16 partials into pp
        gemm4<4><<<dim3(4, 49, 2), 256, 0, stream>>>(
            ob, DIM, 256, WTqkvo + 3 * (size_t)LAYERS * WL + l * WL, DIM, 256,
            nullptr, 0, pp, ND, DIM, 256);
        // reduce + bias + residual + LN1
        red_ln<2><<<NTOK / 4, 256, 0, stream>>>(pp, ND, bo + l * DIM,
                                                ln1g + l * DIM, ln1b + l * DIM, x, xb);
        // FF1 (relu, bf16 out)
        gemm4<1><<<dim3(16, 49, 1), 256, 0, stream>>>(
            xb, DIM, 0, WT1 + (size_t)l * DIM * FFD, DIM, 0,
            b1 + l * FFD, 0, hb, 0, FFD, DIM);
        // FF2, split-K=2, bf16 partials into pp (qkvb dead)
        gemm4<4><<<dim3(4, 49, 2), 256, 0, stream>>>(
            hb, FFD, 1024, WT2 + (size_t)l * FFD * DIM, FFD, 1024,
            nullptr, 0, pp, ND, DIM, 1024);
        // reduce + bias + residual + LN2
        red_ln<2><<<NTOK / 4, 256, 0, stream>>>(pp, ND, b2 + l * DIM,
                                                ln2g + l * DIM, ln2b + l * DIM, x, xb);
    }
    // final LN -> d_out (fp32)
    ln_final<<<NTOK / 4, 256, 0, stream>>>(x, lnfg, lnfb, (float*)d_out);
}

// Round 16
// 953.842 us; speedup vs baseline: 1.0129x; 1.0129x over previous
//
#include <hip/hip_runtime.h>

#define LAYERS 8
#define DIM 512
#define FFD 2048
#define NTOK 6272   // 32 * 196
#define NSEQ 196
#define BATCH 32
#define NHEAD 16
#define HD 32
#define NP 224      // padded seq for attention tiles

typedef unsigned short u16;
typedef __bf16 bf16x8 __attribute__((ext_vector_type(8)));
typedef float f32x4 __attribute__((ext_vector_type(4)));
typedef unsigned short u16x8 __attribute__((ext_vector_type(8)));

__device__ __forceinline__ u16 f2bf(float f) {
    unsigned u = __float_as_uint(f);
    u += 0x7FFF + ((u >> 16) & 1);   // round-to-nearest-even
    return (u16)(u >> 16);
}
__device__ __forceinline__ float bf2f(u16 u) {
    return __uint_as_float((unsigned)u << 16);
}

typedef __attribute__((address_space(1))) void gvoid_t;
typedef __attribute__((address_space(3))) void lvoid_t;
__device__ __forceinline__ void gload_lds16(const void* g, void* l) {
    __builtin_amdgcn_global_load_lds((gvoid_t*)g, (lvoid_t*)l, 16, 0, 0);
}

// ---------------- weight transpose + bf16 convert ----------------
// 4-in-1 for the DxD weights: z = sel*LAYERS + layer, sel in {q,k,v,o}
__global__ __launch_bounds__(256) void transpose_w4(const float* __restrict__ Wq,
                                                    const float* __restrict__ Wk,
                                                    const float* __restrict__ Wv,
                                                    const float* __restrict__ Wo,
                                                    u16* __restrict__ out) {
    __shared__ float t[32][33];
    int z = blockIdx.z;
    int sel = z >> 3, l = z & 7;
    const float* in = (sel == 0) ? Wq : (sel == 1) ? Wk : (sel == 2) ? Wv : Wo;
    size_t ibase = (size_t)l * DIM * DIM;
    size_t obase = (size_t)z * DIM * DIM;
    int n0 = blockIdx.x * 32, k0 = blockIdx.y * 32;
    int tx = threadIdx.x, ty = threadIdx.y;
#pragma unroll
    for (int i = 0; i < 4; ++i)
        t[ty + i * 8][tx] = in[ibase + (size_t)(k0 + ty + i * 8) * DIM + n0 + tx];
    __syncthreads();
#pragma unroll
    for (int i = 0; i < 4; ++i)
        out[obase + (size_t)(n0 + ty + i * 8) * DIM + k0 + tx] = f2bf(t[tx][ty + i * 8]);
}

__global__ __launch_bounds__(256) void transpose_w(const float* __restrict__ in,
                                                   u16* __restrict__ out, int K, int N) {
    __shared__ float t[32][33];
    size_t base = (size_t)blockIdx.z * K * N;
    int n0 = blockIdx.x * 32, k0 = blockIdx.y * 32;
    int tx = threadIdx.x, ty = threadIdx.y;
#pragma unroll
    for (int i = 0; i < 4; ++i)
        t[ty + i * 8][tx] = in[base + (size_t)(k0 + ty + i * 8) * N + n0 + tx];
    __syncthreads();
#pragma unroll
    for (int i = 0; i < 4; ++i)
        out[base + (size_t)(n0 + ty + i * 8) * K + k0 + tx] = f2bf(t[tx][ty + i * 8]);
}

__global__ void pack3_bias(const float* __restrict__ a, const float* __restrict__ b,
                           const float* __restrict__ c, float* __restrict__ o, int n) {
    int i = blockIdx.x * 256 + threadIdx.x;
    if (i < n) { o[i] = a[i]; o[n + i] = b[i]; o[2 * n + i] = c[i]; }
}

// ---------------- gather/unshuffle + pos_emb ----------------
__global__ __launch_bounds__(128) void gather_pos(const float* __restrict__ xenc,
                                                  const int* __restrict__ idx,
                                                  const float* __restrict__ mtok,
                                                  const float* __restrict__ pos,
                                                  float* __restrict__ x, u16* __restrict__ xb) {
    int token = blockIdx.x;
    int b = token / NSEQ, t = token - b * NSEQ;
    int id = idx[token];
    const float* src = (id < 49) ? (xenc + ((size_t)b * 50 + id + 1) * DIM) : mtok;
    int d = threadIdx.x * 4;
    float4 s = *(const float4*)(src + d);
    float4 p = *(const float4*)(pos + (size_t)t * DIM + d);
    float4 r;
    r.x = s.x + p.x; r.y = s.y + p.y; r.z = s.z + p.z; r.w = s.w + p.w;
    *(float4*)(x + (size_t)token * DIM + d) = r;
    ushort4 rb;
    rb.x = f2bf(r.x); rb.y = f2bf(r.y); rb.z = f2bf(r.z); rb.w = f2bf(r.w);
    *(ushort4*)(xb + (size_t)token * DIM + d) = rb;
}

// ---------------- 4-wave 128x128 bf16 MFMA GEMM, BK=64, dbuf + counted vmcnt ----------------
// B^T input (Wt[N][K]); grid.z = slab (weight slab or K-slice)
// EPI 1: relu(A@B+bias)->bf16   EPI 3: A@B+bias->bf16   EPI 4: A@B->bf16 partial
// XOR swizzle ((row&7)<<4) via inverse-swizzled GLOBAL source offset (LDS dest
// linear, required by global_load_lds) + swizzled fragment reads.
// Pipeline (T3/T4): STAGE(next) then s_waitcnt vmcnt(8) — waits only for the
// CURRENT tile's 8 loads, never draining the just-issued prefetch.
// B stays LDS-staged: rounds 12/13 proved direct global->VGPR B either exposes
// L2 latency (r12) or thrashes cache (r13, FETCH 26->67MB).
// Epilogue: C bounced through LDS -> 8x u16x8 coalesced stores per thread.
// Cross-thread LDS exchange REQUIRES __syncthreads (round-10 race).
template<int EPI>
__global__ __launch_bounds__(256) void gemm4(
    const u16* __restrict__ A, int lda, long long zsA,
    const u16* __restrict__ Bt, int ldb, long long zsB,
    const float* __restrict__ bias, long long zsBias,
    u16* __restrict__ outB, long long zsOut,
    int N, int K) {
    __shared__ u16 smem[32768];        // 64KB: As dbuf [0..16383], Bs dbuf [16384..32767]
    int tid = threadIdx.x;
    int lane = tid & 63, wid = tid >> 6;
    int z = blockIdx.z;
    const u16* Az = A + (size_t)z * zsA;
    const u16* Bz = Bt + (size_t)z * zsB;
    int m0 = blockIdx.y * 128, n0 = blockIdx.x * 128;
    int l16 = lane & 15, kq = lane >> 4;
    int wm = (wid >> 1) * 64, wn = (wid & 1) * 64;

    f32x4 acc[4][4];
    f32x4 zero = {0.f, 0.f, 0.f, 0.f};
#pragma unroll
    for (int a = 0; a < 4; ++a)
#pragma unroll
        for (int b = 0; b < 4; ++b) acc[a][b] = zero;

#define STAGE(buf, kk)                                                             \
    {                                                                              \
        u16* asb_ = smem + (buf) * 8192;                                           \
        u16* bsb_ = smem + 16384 + (buf) * 8192;                                   \
        _Pragma("unroll")                                                          \
        for (int i_ = 0; i_ < 4; ++i_) {                                           \
            int c_ = i_ * 256 + tid;               /* 16B chunk id 0..1023 */      \
            int row_ = c_ >> 3;                    /* 128B (64 bf16) rows */       \
            int kof_ = ((c_ & 7) * 16) ^ ((row_ & 7) << 4);                        \
            gload_lds16((const char*)Az + ((size_t)(m0 + row_) * lda + (kk)) * 2 + kof_, \
                        (char*)asb_ + (size_t)c_ * 16);                            \
            gload_lds16((const char*)Bz + ((size_t)(n0 + row_) * ldb + (kk)) * 2 + kof_, \
                        (char*)bsb_ + (size_t)c_ * 16);                            \
        }                                                                          \
    }

    int nk = K >> 6;
    STAGE(0, 0);                       // 8 vmem ops in flight (tile 0)
    for (int kt = 0; kt < nk; ++kt) {
        int cur = kt & 1;
        if (kt + 1 < nk) {
            STAGE(cur ^ 1, (kt + 1) << 6);                     // +8 (tile kt+1)
            asm volatile("s_waitcnt vmcnt(8)" ::: "memory");   // tile kt landed
        } else {
            asm volatile("s_waitcnt vmcnt(0)" ::: "memory");   // final drain
        }
        __builtin_amdgcn_s_barrier();
        const char* Ac = (const char*)(smem + cur * 8192);
        const char* Bc = (const char*)(smem + 16384 + cur * 8192);
#pragma unroll
        for (int kh = 0; kh < 2; ++kh) {
            bf16x8 af[4], bfr[4];
#pragma unroll
            for (int mr = 0; mr < 4; ++mr) {
                int row = wm + mr * 16 + l16;
                int cb = (kh * 64 + kq * 16) ^ ((row & 7) << 4);
                af[mr] = *(const bf16x8*)(Ac + row * 128 + cb);
            }
#pragma unroll
            for (int nc = 0; nc < 4; ++nc) {
                int row = wn + nc * 16 + l16;
                int cb = (kh * 64 + kq * 16) ^ ((row & 7) << 4);
                bfr[nc] = *(const bf16x8*)(Bc + row * 128 + cb);
            }
#pragma unroll
            for (int mr = 0; mr < 4; ++mr)
#pragma unroll
                for (int nc = 0; nc < 4; ++nc)
                    acc[mr][nc] = __builtin_amdgcn_mfma_f32_16x16x32_bf16(af[mr], bfr[nc],
                                                                          acc[mr][nc], 0, 0, 0);
        }
        __builtin_amdgcn_s_barrier();  // all reads of buf cur done before it is re-staged
    }
#undef STAGE

    // ---- epilogue: bounce C tile through LDS (dead after K-loop) ----
    __syncthreads();                   // full drain: safe to repurpose smem
    const float* biasz = (EPI != 4) ? bias + (size_t)z * zsBias : nullptr;
    const int CLD = 136;               // padded u16 row stride (272B)
    u16* Cs = smem;                    // 128*136 = 17408 u16 <= 32768
#pragma unroll
    for (int mr = 0; mr < 4; ++mr)
#pragma unroll
        for (int nc = 0; nc < 4; ++nc)
#pragma unroll
            for (int i = 0; i < 4; ++i) {
                int rl = wm + mr * 16 + kq * 4 + i;   // row = (lane>>4)*4 + reg
                int cl = wn + nc * 16 + l16;          // col = lane&15
                float v = acc[mr][nc][i];
                if (EPI == 1) { v += biasz[n0 + cl]; v = v > 0.f ? v : 0.f; }
                else if (EPI == 3) { v += biasz[n0 + cl]; }
                Cs[rl * CLD + cl] = f2bf(v);
            }
    __syncthreads();                   // lgkmcnt(0) drain + barrier: writes visible
#pragma unroll
    for (int k = 0; k < 8; ++k) {
        int g = k * 256 + tid;                        // 2048 chunks of 16B
        int r = g >> 4, ch = g & 15;
        u16x8 val = *(const u16x8*)&Cs[r * CLD + ch * 8];
        *(u16x8*)&outB[(size_t)z * zsOut + (size_t)(m0 + r) * N + n0 + ch * 8] = val;
    }
}

// ---------------- fused split-K reduce (NS bf16 partial slabs) + bias + residual + LN ----------------
template<int NS>
__global__ __launch_bounds__(256) void red_ln(const u16* __restrict__ p0, long long ps,
                                              const float* __restrict__ bias,
                                              const float* __restrict__ gg,
                                              const float* __restrict__ bb,
                                              float* __restrict__ x, u16* __restrict__ xb) {
    int t = blockIdx.x * 4 + (threadIdx.x >> 6);
    int lane = threadIdx.x & 63;
    size_t base = (size_t)t * DIM;
    int c0 = lane * 8;
    float v[8];
    {
        u16x8 pa = *(const u16x8*)(p0 + base + c0);
#pragma unroll
        for (int i = 0; i < 8; ++i) v[i] = bf2f(pa[i]);
    }
#pragma unroll
    for (int s2i = 1; s2i < NS; ++s2i) {
        u16x8 pb = *(const u16x8*)(p0 + (size_t)s2i * ps + base + c0);
#pragma unroll
        for (int i = 0; i < 8; ++i) v[i] += bf2f(pb[i]);
    }
    float4 xa = *(const float4*)(x + base + c0);
    float4 xc = *(const float4*)(x + base + c0 + 4);
    float4 ba = *(const float4*)(bias + c0);
    float4 bc = *(const float4*)(bias + c0 + 4);
    float xs[8] = {xa.x, xa.y, xa.z, xa.w, xc.x, xc.y, xc.z, xc.w};
    float bs[8] = {ba.x, ba.y, ba.z, ba.w, bc.x, bc.y, bc.z, bc.w};
    float s = 0.f, s2 = 0.f;
#pragma unroll
    for (int i = 0; i < 8; ++i) {
        v[i] += bs[i] + xs[i];
        s += v[i]; s2 += v[i] * v[i];
    }
#pragma unroll
    for (int off = 32; off; off >>= 1) { s += __shfl_xor(s, off); s2 += __shfl_xor(s2, off); }
    float m = s * (1.f / 512.f);
    float var = s2 * (1.f / 512.f) - m * m;
    float rs = rsqrtf(var + 1e-5f);
    float4 ga = *(const float4*)(gg + c0);
    float4 gc = *(const float4*)(gg + c0 + 4);
    float4 b0 = *(const float4*)(bb + c0);
    float4 b1 = *(const float4*)(bb + c0 + 4);
    float gs[8] = {ga.x, ga.y, ga.z, ga.w, gc.x, gc.y, gc.z, gc.w};
    float os[8] = {b0.x, b0.y, b0.z, b0.w, b1.x, b1.y, b1.z, b1.w};
    float o[8];
    u16x8 ob16;
#pragma unroll
    for (int i = 0; i < 8; ++i) {
        o[i] = (v[i] - m) * rs * gs[i] + os[i];
        ob16[i] = f2bf(o[i]);
    }
    float4 o0 = {o[0], o[1], o[2], o[3]};
    float4 o1 = {o[4], o[5], o[6], o[7]};
    *(float4*)(x + base + c0) = o0;
    *(float4*)(x + base + c0 + 4) = o1;
    *(u16x8*)(xb + base + c0) = ob16;
}

// ---------------- MFMA flash attention, 2 blocks per (b,h), 4 waves each ----------------
__global__ __launch_bounds__(256) void attn_mfma(const u16* __restrict__ qkvb,
                                                 u16* __restrict__ ob) {
    __shared__ u16 Ks[NP * 32];            // [224][32] row-major
    __shared__ u16 VTs[32 * 232];          // [32][232] V transposed
    __shared__ u16 Ps[4][16 * 128];        // per-wave P panel, 256B rows
    int bh = blockIdx.x >> 1, half = blockIdx.x & 1;
    int b = bh >> 4, h = bh & 15;
    int tid = threadIdx.x, lane = tid & 63, wid = tid >> 6;
    int l16 = lane & 15, kq = lane >> 4;
    const size_t MS = (size_t)NTOK * DIM;
    const u16* qg = qkvb + ((size_t)b * NSEQ) * DIM + h * HD;
    const u16* kg = qg + MS;
    const u16* vg = qg + 2 * MS;

    for (int c = tid; c < 784; c += 256) {
        int row = c >> 2, ch = c & 3;
        gload_lds16(kg + (size_t)row * DIM + ch * 8, (char*)Ks + c * 16);
    }
    for (int i = tid; i < 448; i += 256) ((unsigned*)(Ks + 196 * 32))[i] = 0;
    for (int i = tid; i < 1568; i += 256) {
        int j = i >> 3, d0 = (i & 7) * 4;
        ushort4 vv = *(const ushort4*)(vg + (size_t)j * DIM + d0);
        VTs[(d0 + 0) * 232 + j] = vv.x;
        VTs[(d0 + 1) * 232 + j] = vv.y;
        VTs[(d0 + 2) * 232 + j] = vv.z;
        VTs[(d0 + 3) * 232 + j] = vv.w;
    }
    for (int i = tid; i < 1024; i += 256) {
        int d = i >> 5, j = 196 + (i & 31);
        VTs[d * 232 + j] = 0;
    }
    __syncthreads();

    const float scale = 0.17677669529663687f;   // 1/sqrt(32)
    char* psb = (char*)&Ps[wid][0];
    int pend = half ? 13 : 7;

    for (int p = half * 7 + wid; p < pend; p += 4) {
        int r0 = p * 16;
        int qrow = r0 + l16; if (qrow > 195) qrow = 195;
        bf16x8 qf = *(const bf16x8*)(qg + (size_t)qrow * DIM + kq * 8);

        f32x4 z4 = {0.f, 0.f, 0.f, 0.f};
        f32x4 s[14];
#pragma unroll
        for (int ct = 0; ct < 14; ++ct) {
            bf16x8 kf = *(const bf16x8*)&Ks[(ct * 16 + l16) * 32 + kq * 8];
            s[ct] = __builtin_amdgcn_mfma_f32_16x16x32_bf16(qf, kf, z4, 0, 0, 0);
        }
        bool v12 = (l16 < 4);   // tile 12 cols 192..207 valid iff l16<4
        float mx[4], sum[4], inv[4];
#pragma unroll
        for (int i = 0; i < 4; ++i) {
            float m = -1e30f;
#pragma unroll
            for (int ct = 0; ct < 12; ++ct) m = fmaxf(m, s[ct][i]);
            if (v12) m = fmaxf(m, s[12][i]);
            mx[i] = m * scale;
        }
#pragma unroll
        for (int off = 8; off; off >>= 1)
#pragma unroll
            for (int i = 0; i < 4; ++i) mx[i] = fmaxf(mx[i], __shfl_xor(mx[i], off));
#pragma unroll
        for (int i = 0; i < 4; ++i) sum[i] = 0.f;
#pragma unroll
        for (int ct = 0; ct < 14; ++ct)
#pragma unroll
            for (int i = 0; i < 4; ++i) {
                bool valid = (ct < 12) || (ct == 12 && v12);
                float e = valid ? __expf(s[ct][i] * scale - mx[i]) : 0.f;
                s[ct][i] = e;
                sum[i] += e;
            }
#pragma unroll
        for (int off = 8; off; off >>= 1)
#pragma unroll
            for (int i = 0; i < 4; ++i) sum[i] += __shfl_xor(sum[i], off);
#pragma unroll
        for (int i = 0; i < 4; ++i) inv[i] = 1.f / sum[i];

        f32x4 o0 = {0.f, 0.f, 0.f, 0.f}, o1 = {0.f, 0.f, 0.f, 0.f};
        // phase A: col tiles 0..7 -> Ps; PV k-tiles 0..3
#pragma unroll
        for (int ct = 0; ct < 8; ++ct)
#pragma unroll
            for (int i = 0; i < 4; ++i) {
                int rl = kq * 4 + i;
                int byte = rl * 256 + (((ct * 16 + l16) * 2) ^ ((rl & 7) << 4));
                *(u16*)(psb + byte) = f2bf(s[ct][i]);
            }
#pragma unroll
        for (int kt = 0; kt < 4; ++kt) {
            int K2 = (kt * 64 + kq * 16) ^ ((l16 & 7) << 4);
            bf16x8 pa = *(const bf16x8*)(psb + l16 * 256 + K2);
            bf16x8 va = *(const bf16x8*)&VTs[l16 * 232 + kt * 32 + kq * 8];
            bf16x8 vb = *(const bf16x8*)&VTs[(16 + l16) * 232 + kt * 32 + kq * 8];
            o0 = __builtin_amdgcn_mfma_f32_16x16x32_bf16(pa, va, o0, 0, 0, 0);
            o1 = __builtin_amdgcn_mfma_f32_16x16x32_bf16(pa, vb, o1, 0, 0, 0);
        }
        // phase B: col tiles 8..13 -> Ps (reused); PV k-tiles 4..6
#pragma unroll
        for (int ct = 8; ct < 14; ++ct)
#pragma unroll
            for (int i = 0; i < 4; ++i) {
                int rl = kq * 4 + i;
                int byte = rl * 256 + ((((ct - 8) * 16 + l16) * 2) ^ ((rl & 7) << 4));
                *(u16*)(psb + byte) = f2bf(s[ct][i]);
            }
#pragma unroll
        for (int kt = 4; kt < 7; ++kt) {
            int K2 = ((kt - 4) * 64 + kq * 16) ^ ((l16 & 7) << 4);
            bf16x8 pa = *(const bf16x8*)(psb + l16 * 256 + K2);
            bf16x8 va = *(const bf16x8*)&VTs[l16 * 232 + kt * 32 + kq * 8];
            bf16x8 vb = *(const bf16x8*)&VTs[(16 + l16) * 232 + kt * 32 + kq * 8];
            o0 = __builtin_amdgcn_mfma_f32_16x16x32_bf16(pa, va, o0, 0, 0, 0);
            o1 = __builtin_amdgcn_mfma_f32_16x16x32_bf16(pa, vb, o1, 0, 0, 0);
        }
#pragma unroll
        for (int i = 0; i < 4; ++i) {
            int row = r0 + kq * 4 + i;
            if (row < NSEQ) {
                size_t rb = ((size_t)b * NSEQ + row) * DIM + h * HD;
                ob[rb + l16] = f2bf(o0[i] * inv[i]);
                ob[rb + 16 + l16] = f2bf(o1[i] * inv[i]);
            }
        }
    }
}

// ---------------- final LayerNorm, one wave per token ----------------
__global__ __launch_bounds__(256) void ln_final(const float* __restrict__ y,
                                                const float* __restrict__ gg,
                                                const float* __restrict__ bb,
                                                float* __restrict__ xout) {
    int t = blockIdx.x * 4 + (threadIdx.x >> 6);
    int lane = threadIdx.x & 63;
    const float* row = y + (size_t)t * DIM;
    float4 a = *(const float4*)(row + lane * 4);
    float4 c = *(const float4*)(row + 256 + lane * 4);
    float s = a.x + a.y + a.z + a.w + c.x + c.y + c.z + c.w;
    float s2 = a.x * a.x + a.y * a.y + a.z * a.z + a.w * a.w
             + c.x * c.x + c.y * c.y + c.z * c.z + c.w * c.w;
#pragma unroll
    for (int off = 32; off; off >>= 1) { s += __shfl_xor(s, off); s2 += __shfl_xor(s2, off); }
    float m = s * (1.f / 512.f);
    float var = s2 * (1.f / 512.f) - m * m;
    float rs = rsqrtf(var + 1e-5f);
    float4 g0 = *(const float4*)(gg + lane * 4);
    float4 g1 = *(const float4*)(gg + 256 + lane * 4);
    float4 b0 = *(const float4*)(bb + lane * 4);
    float4 b1 = *(const float4*)(bb + 256 + lane * 4);
    float4 o0, o1;
    o0.x = (a.x - m) * rs * g0.x + b0.x;
    o0.y = (a.y - m) * rs * g0.y + b0.y;
    o0.z = (a.z - m) * rs * g0.z + b0.z;
    o0.w = (a.w - m) * rs * g0.w + b0.w;
    o1.x = (c.x - m) * rs * g1.x + b1.x;
    o1.y = (c.y - m) * rs * g1.y + b1.y;
    o1.z = (c.z - m) * rs * g1.z + b1.z;
    o1.w = (c.w - m) * rs * g1.w + b1.w;
    *(float4*)(xout + (size_t)t * DIM + lane * 4) = o0;
    *(float4*)(xout + (size_t)t * DIM + 256 + lane * 4) = o1;
}

extern "C" void kernel_launch(void* const* d_in, const int* in_sizes, int n_in,
                              void* d_out, int out_size, void* d_ws, size_t ws_size,
                              hipStream_t stream) {
    const float* xenc = (const float*)d_in[0];
    const int*   idxr = (const int*)d_in[1];
    const float* mtok = (const float*)d_in[2];
    const float* pos  = (const float*)d_in[3];
    const float* Wq = (const float*)d_in[4];  const float* bq = (const float*)d_in[5];
    const float* Wk = (const float*)d_in[6];  const float* bk = (const float*)d_in[7];
    const float* Wv = (const float*)d_in[8];  const float* bv = (const float*)d_in[9];
    const float* Wo = (const float*)d_in[10]; const float* bo = (const float*)d_in[11];
    const float* ln1g = (const float*)d_in[12]; const float* ln1b = (const float*)d_in[13];
    const float* W1 = (const float*)d_in[14]; const float* b1 = (const float*)d_in[15];
    const float* W2 = (const float*)d_in[16]; const float* b2 = (const float*)d_in[17];
    const float* ln2g = (const float*)d_in[18]; const float* ln2b = (const float*)d_in[19];
    const float* lnfg = (const float*)d_in[20]; const float* lnfb = (const float*)d_in[21];

    // ---- workspace carve ----
    char* w = (char*)d_ws;
    u16* WTqkvo = (u16*)w; w += (size_t)4 * LAYERS * DIM * DIM * 2;     // bf16 W^T (q,k,v,o)
    u16* WT1    = (u16*)w; w += (size_t)LAYERS * DIM * FFD * 2;         // [8][2048][512]
    u16* WT2    = (u16*)w; w += (size_t)LAYERS * FFD * DIM * 2;         // [8][512][2048]
    float* bqkv = (float*)w; w += (size_t)3 * LAYERS * DIM * 4;         // [3][8][512]
    float* x    = (float*)w; w += (size_t)NTOK * DIM * 4;               // fp32 residual stream
    u16*   xb   = (u16*)w;  w += (size_t)NTOK * DIM * 2;                // bf16 copy of x
    u16*   qkvb = (u16*)w;  w += (size_t)3 * NTOK * DIM * 2;            // q,k,v bf16
    u16*   ob   = (u16*)w;  w += (size_t)NTOK * DIM * 2;                // attention out bf16
    u16*   hb   = (u16*)w;  w += (size_t)NTOK * FFD * 2;                // FF hidden bf16
    size_t need = (size_t)(w - (char*)d_ws);
    if (ws_size < need) return;

    // bf16 split-K partial slabs (2 x ND u16), aliased into qkvb (dead after attn / during FF2)
    u16* pp = qkvb;
    const long long ND = (long long)NTOK * DIM;

    const size_t WL = (size_t)DIM * DIM;

    // ---- weight prep ----
    transpose_w4<<<dim3(DIM / 32, DIM / 32, 4 * LAYERS), dim3(32, 8), 0, stream>>>(Wq, Wk, Wv, Wo, WTqkvo);
    transpose_w<<<dim3(FFD / 32, DIM / 32, LAYERS), dim3(32, 8), 0, stream>>>(W1, WT1, DIM, FFD);
    transpose_w<<<dim3(DIM / 32, FFD / 32, LAYERS), dim3(32, 8), 0, stream>>>(W2, WT2, FFD, DIM);
    pack3_bias<<<(LAYERS * DIM + 255) / 256, 256, 0, stream>>>(bq, bk, bv, bqkv, LAYERS * DIM);

    // ---- embed ----
    gather_pos<<<NTOK, 128, 0, stream>>>(xenc, idxr, mtok, pos, x, xb);

    for (int l = 0; l < LAYERS; ++l) {
        // QKV -> bf16 (z = weight slab 0..2)
        gemm4<3><<<dim3(4, 49, 3), 256, 0, stream>>>(
            xb, DIM, 0, WTqkvo + l * WL, DIM, (long long)LAYERS * WL,
            bqkv + l * DIM, (long long)LAYERS * DIM,
            qkvb, ND, DIM, DIM);
        // MFMA attention (2 blocks per (b,h))
        attn_mfma<<<BATCH * NHEAD * 2, 256, 0, stream>>>(qkvb, ob);
        // out projection, split-K=2 (z = K-slice), bf16 partials into pp
        gemm4<4><<<dim3(4, 49, 2), 256, 0, stream>>>(
            ob, DIM, 256, WTqkvo + 3 * (size_t)LAYERS * WL + l * WL, DIM, 256,
            nullptr, 0, pp, ND, DIM, 256);
        // reduce + bias + residual + LN1
        red_ln<2><<<NTOK / 4, 256, 0, stream>>>(pp, ND, bo + l * DIM,
                                                ln1g + l * DIM, ln1b + l * DIM, x, xb);
        // FF1 (relu, bf16 out)
        gemm4<1><<<dim3(16, 49, 1), 256, 0, stream>>>(
            xb, DIM, 0, WT1 + (size_t)l * DIM * FFD, DIM, 0,
            b1 + l * FFD, 0, hb, 0, FFD, DIM);
        // FF2, split-K=2, bf16 partials into pp (qkvb dead)
        gemm4<4><<<dim3(4, 49, 2), 256, 0, stream>>>(
            hb, FFD, 1024, WT2 + (size_t)l * FFD * DIM, FFD, 1024,
            nullptr, 0, pp, ND, DIM, 1024);
        // reduce + bias + residual + LN2
        red_ln<2><<<NTOK / 4, 256, 0, stream>>>(pp, ND, b2 + l * DIM,
                                                ln2g + l * DIM, ln2b + l * DIM, x, xb);
    }
    // final LN -> d_out (fp32)
    ln_final<<<NTOK / 4, 256, 0, stream>>>(x, lnfg, lnfb, (float*)d_out);
}

// Round 17
// 913.229 us; speedup vs baseline: 1.0579x; 1.0445x over previous
//
#include <hip/hip_runtime.h>

#define LAYERS 8
#define DIM 512
#define FFD 2048
#define NTOK 6272   // 32 * 196
#define NSEQ 196
#define BATCH 32
#define NHEAD 16
#define HD 32
#define NP 224      // padded seq for attention tiles

typedef unsigned short u16;
typedef __bf16 bf16x8 __attribute__((ext_vector_type(8)));
typedef float f32x4 __attribute__((ext_vector_type(4)));
typedef unsigned short u16x8 __attribute__((ext_vector_type(8)));

__device__ __forceinline__ u16 f2bf(float f) {
    unsigned u = __float_as_uint(f);
    u += 0x7FFF + ((u >> 16) & 1);   // round-to-nearest-even
    return (u16)(u >> 16);
}
__device__ __forceinline__ float bf2f(u16 u) {
    return __uint_as_float((unsigned)u << 16);
}

typedef __attribute__((address_space(1))) void gvoid_t;
typedef __attribute__((address_space(3))) void lvoid_t;
__device__ __forceinline__ void gload_lds16(const void* g, void* l) {
    __builtin_amdgcn_global_load_lds((gvoid_t*)g, (lvoid_t*)l, 16, 0, 0);
}

// ---------------- weight transpose + bf16 convert ----------------
// 4-in-1 for the DxD weights: z = sel*LAYERS + layer, sel in {q,k,v,o}
__global__ __launch_bounds__(256) void transpose_w4(const float* __restrict__ Wq,
                                                    const float* __restrict__ Wk,
                                                    const float* __restrict__ Wv,
                                                    const float* __restrict__ Wo,
                                                    u16* __restrict__ out) {
    __shared__ float t[32][33];
    int z = blockIdx.z;
    int sel = z >> 3, l = z & 7;
    const float* in = (sel == 0) ? Wq : (sel == 1) ? Wk : (sel == 2) ? Wv : Wo;
    size_t ibase = (size_t)l * DIM * DIM;
    size_t obase = (size_t)z * DIM * DIM;
    int n0 = blockIdx.x * 32, k0 = blockIdx.y * 32;
    int tx = threadIdx.x, ty = threadIdx.y;
#pragma unroll
    for (int i = 0; i < 4; ++i)
        t[ty + i * 8][tx] = in[ibase + (size_t)(k0 + ty + i * 8) * DIM + n0 + tx];
    __syncthreads();
#pragma unroll
    for (int i = 0; i < 4; ++i)
        out[obase + (size_t)(n0 + ty + i * 8) * DIM + k0 + tx] = f2bf(t[tx][ty + i * 8]);
}

__global__ __launch_bounds__(256) void transpose_w(const float* __restrict__ in,
                                                   u16* __restrict__ out, int K, int N) {
    __shared__ float t[32][33];
    size_t base = (size_t)blockIdx.z * K * N;
    int n0 = blockIdx.x * 32, k0 = blockIdx.y * 32;
    int tx = threadIdx.x, ty = threadIdx.y;
#pragma unroll
    for (int i = 0; i < 4; ++i)
        t[ty + i * 8][tx] = in[base + (size_t)(k0 + ty + i * 8) * N + n0 + tx];
    __syncthreads();
#pragma unroll
    for (int i = 0; i < 4; ++i)
        out[base + (size_t)(n0 + ty + i * 8) * K + k0 + tx] = f2bf(t[tx][ty + i * 8]);
}

__global__ void pack3_bias(const float* __restrict__ a, const float* __restrict__ b,
                           const float* __restrict__ c, float* __restrict__ o, int n) {
    int i = blockIdx.x * 256 + threadIdx.x;
    if (i < n) { o[i] = a[i]; o[n + i] = b[i]; o[2 * n + i] = c[i]; }
}

// ---------------- gather/unshuffle + pos_emb (bf16 residual stream only) ----------------
__global__ __launch_bounds__(128) void gather_pos(const float* __restrict__ xenc,
                                                  const int* __restrict__ idx,
                                                  const float* __restrict__ mtok,
                                                  const float* __restrict__ pos,
                                                  u16* __restrict__ xb) {
    int token = blockIdx.x;
    int b = token / NSEQ, t = token - b * NSEQ;
    int id = idx[token];
    const float* src = (id < 49) ? (xenc + ((size_t)b * 50 + id + 1) * DIM) : mtok;
    int d = threadIdx.x * 4;
    float4 s = *(const float4*)(src + d);
    float4 p = *(const float4*)(pos + (size_t)t * DIM + d);
    ushort4 rb;
    rb.x = f2bf(s.x + p.x); rb.y = f2bf(s.y + p.y);
    rb.z = f2bf(s.z + p.z); rb.w = f2bf(s.w + p.w);
    *(ushort4*)(xb + (size_t)token * DIM + d) = rb;
}

// ---------------- 4-wave 128x128 bf16 MFMA GEMM, BK=64, dbuf + counted vmcnt ----------------
// B^T input (Wt[N][K]); grid.z = slab (weight slab or K-slice)
// EPI 1: relu(A@B+bias)->bf16   EPI 3: A@B+bias->bf16   EPI 4: A@B->bf16 partial
// XOR swizzle ((row&7)<<4) via inverse-swizzled GLOBAL source offset (LDS dest
// linear, required by global_load_lds) + swizzled fragment reads.
// Pipeline (T3/T4): STAGE(next) then s_waitcnt vmcnt(8) — waits only for the
// CURRENT tile's 8 loads, never draining the just-issued prefetch.
// B stays LDS-staged: rounds 12/13 proved direct global->VGPR B either exposes
// L2 latency (r12) or thrashes cache (r13, FETCH 26->67MB).
// Epilogue: C bounced through LDS -> 8x u16x8 coalesced stores per thread.
// Cross-thread LDS exchange REQUIRES __syncthreads (round-10 race).
template<int EPI>
__global__ __launch_bounds__(256) void gemm4(
    const u16* __restrict__ A, int lda, long long zsA,
    const u16* __restrict__ Bt, int ldb, long long zsB,
    const float* __restrict__ bias, long long zsBias,
    u16* __restrict__ outB, long long zsOut,
    int N, int K) {
    __shared__ u16 smem[32768];        // 64KB: As dbuf [0..16383], Bs dbuf [16384..32767]
    int tid = threadIdx.x;
    int lane = tid & 63, wid = tid >> 6;
    int z = blockIdx.z;
    const u16* Az = A + (size_t)z * zsA;
    const u16* Bz = Bt + (size_t)z * zsB;
    int m0 = blockIdx.y * 128, n0 = blockIdx.x * 128;
    int l16 = lane & 15, kq = lane >> 4;
    int wm = (wid >> 1) * 64, wn = (wid & 1) * 64;

    f32x4 acc[4][4];
    f32x4 zero = {0.f, 0.f, 0.f, 0.f};
#pragma unroll
    for (int a = 0; a < 4; ++a)
#pragma unroll
        for (int b = 0; b < 4; ++b) acc[a][b] = zero;

#define STAGE(buf, kk)                                                             \
    {                                                                              \
        u16* asb_ = smem + (buf) * 8192;                                           \
        u16* bsb_ = smem + 16384 + (buf) * 8192;                                   \
        _Pragma("unroll")                                                          \
        for (int i_ = 0; i_ < 4; ++i_) {                                           \
            int c_ = i_ * 256 + tid;               /* 16B chunk id 0..1023 */      \
            int row_ = c_ >> 3;                    /* 128B (64 bf16) rows */       \
            int kof_ = ((c_ & 7) * 16) ^ ((row_ & 7) << 4);                        \
            gload_lds16((const char*)Az + ((size_t)(m0 + row_) * lda + (kk)) * 2 + kof_, \
                        (char*)asb_ + (size_t)c_ * 16);                            \
            gload_lds16((const char*)Bz + ((size_t)(n0 + row_) * ldb + (kk)) * 2 + kof_, \
                        (char*)bsb_ + (size_t)c_ * 16);                            \
        }                                                                          \
    }

    int nk = K >> 6;
    STAGE(0, 0);                       // 8 vmem ops in flight (tile 0)
    for (int kt = 0; kt < nk; ++kt) {
        int cur = kt & 1;
        if (kt + 1 < nk) {
            STAGE(cur ^ 1, (kt + 1) << 6);                     // +8 (tile kt+1)
            asm volatile("s_waitcnt vmcnt(8)" ::: "memory");   // tile kt landed
        } else {
            asm volatile("s_waitcnt vmcnt(0)" ::: "memory");   // final drain
        }
        __builtin_amdgcn_s_barrier();
        const char* Ac = (const char*)(smem + cur * 8192);
        const char* Bc = (const char*)(smem + 16384 + cur * 8192);
#pragma unroll
        for (int kh = 0; kh < 2; ++kh) {
            bf16x8 af[4], bfr[4];
#pragma unroll
            for (int mr = 0; mr < 4; ++mr) {
                int row = wm + mr * 16 + l16;
                int cb = (kh * 64 + kq * 16) ^ ((row & 7) << 4);
                af[mr] = *(const bf16x8*)(Ac + row * 128 + cb);
            }
#pragma unroll
            for (int nc = 0; nc < 4; ++nc) {
                int row = wn + nc * 16 + l16;
                int cb = (kh * 64 + kq * 16) ^ ((row & 7) << 4);
                bfr[nc] = *(const bf16x8*)(Bc + row * 128 + cb);
            }
#pragma unroll
            for (int mr = 0; mr < 4; ++mr)
#pragma unroll
                for (int nc = 0; nc < 4; ++nc)
                    acc[mr][nc] = __builtin_amdgcn_mfma_f32_16x16x32_bf16(af[mr], bfr[nc],
                                                                          acc[mr][nc], 0, 0, 0);
        }
        __builtin_amdgcn_s_barrier();  // all reads of buf cur done before it is re-staged
    }
#undef STAGE

    // ---- epilogue: bounce C tile through LDS (dead after K-loop) ----
    __syncthreads();                   // full drain: safe to repurpose smem
    const float* biasz = (EPI != 4) ? bias + (size_t)z * zsBias : nullptr;
    const int CLD = 136;               // padded u16 row stride (272B)
    u16* Cs = smem;                    // 128*136 = 17408 u16 <= 32768
#pragma unroll
    for (int mr = 0; mr < 4; ++mr)
#pragma unroll
        for (int nc = 0; nc < 4; ++nc)
#pragma unroll
            for (int i = 0; i < 4; ++i) {
                int rl = wm + mr * 16 + kq * 4 + i;   // row = (lane>>4)*4 + reg
                int cl = wn + nc * 16 + l16;          // col = lane&15
                float v = acc[mr][nc][i];
                if (EPI == 1) { v += biasz[n0 + cl]; v = v > 0.f ? v : 0.f; }
                else if (EPI == 3) { v += biasz[n0 + cl]; }
                Cs[rl * CLD + cl] = f2bf(v);
            }
    __syncthreads();                   // lgkmcnt(0) drain + barrier: writes visible
#pragma unroll
    for (int k = 0; k < 8; ++k) {
        int g = k * 256 + tid;                        // 2048 chunks of 16B
        int r = g >> 4, ch = g & 15;
        u16x8 val = *(const u16x8*)&Cs[r * CLD + ch * 8];
        *(u16x8*)&outB[(size_t)z * zsOut + (size_t)(m0 + r) * N + n0 + ch * 8] = val;
    }
}

// ---------------- fused split-K reduce (NS bf16 partials) + bias + bf16 residual + LN ----------------
// Residual stream lives in bf16 only (the GEMMs consume bf16 anyway); in-place
// read/write of xb is per-thread-local so no barrier needed.
template<int NS>
__global__ __launch_bounds__(256) void red_ln(const u16* __restrict__ p0, long long ps,
                                              const float* __restrict__ bias,
                                              const float* __restrict__ gg,
                                              const float* __restrict__ bb,
                                              u16* __restrict__ xb) {
    int t = blockIdx.x * 4 + (threadIdx.x >> 6);
    int lane = threadIdx.x & 63;
    size_t base = (size_t)t * DIM;
    int c0 = lane * 8;
    float v[8];
    {
        u16x8 pa = *(const u16x8*)(p0 + base + c0);
#pragma unroll
        for (int i = 0; i < 8; ++i) v[i] = bf2f(pa[i]);
    }
#pragma unroll
    for (int s2i = 1; s2i < NS; ++s2i) {
        u16x8 pb = *(const u16x8*)(p0 + (size_t)s2i * ps + base + c0);
#pragma unroll
        for (int i = 0; i < 8; ++i) v[i] += bf2f(pb[i]);
    }
    u16x8 xr = *(const u16x8*)(xb + base + c0);
    float4 ba = *(const float4*)(bias + c0);
    float4 bc = *(const float4*)(bias + c0 + 4);
    float bs[8] = {ba.x, ba.y, ba.z, ba.w, bc.x, bc.y, bc.z, bc.w};
    float s = 0.f, s2 = 0.f;
#pragma unroll
    for (int i = 0; i < 8; ++i) {
        v[i] += bs[i] + bf2f(xr[i]);
        s += v[i]; s2 += v[i] * v[i];
    }
#pragma unroll
    for (int off = 32; off; off >>= 1) { s += __shfl_xor(s, off); s2 += __shfl_xor(s2, off); }
    float m = s * (1.f / 512.f);
    float var = s2 * (1.f / 512.f) - m * m;
    float rs = rsqrtf(var + 1e-5f);
    float4 ga = *(const float4*)(gg + c0);
    float4 gc = *(const float4*)(gg + c0 + 4);
    float4 b0 = *(const float4*)(bb + c0);
    float4 b1 = *(const float4*)(bb + c0 + 4);
    float gs[8] = {ga.x, ga.y, ga.z, ga.w, gc.x, gc.y, gc.z, gc.w};
    float os[8] = {b0.x, b0.y, b0.z, b0.w, b1.x, b1.y, b1.z, b1.w};
    u16x8 ob16;
#pragma unroll
    for (int i = 0; i < 8; ++i)
        ob16[i] = f2bf((v[i] - m) * rs * gs[i] + os[i]);
    *(u16x8*)(xb + base + c0) = ob16;
}

// ---------------- MFMA flash attention, 2 blocks per (b,h), 4 waves each ----------------
__global__ __launch_bounds__(256) void attn_mfma(const u16* __restrict__ qkvb,
                                                 u16* __restrict__ ob) {
    __shared__ u16 Ks[NP * 32];            // [224][32] row-major
    __shared__ u16 VTs[32 * 232];          // [32][232] V transposed
    __shared__ u16 Ps[4][16 * 128];        // per-wave P panel, 256B rows
    int bh = blockIdx.x >> 1, half = blockIdx.x & 1;
    int b = bh >> 4, h = bh & 15;
    int tid = threadIdx.x, lane = tid & 63, wid = tid >> 6;
    int l16 = lane & 15, kq = lane >> 4;
    const size_t MS = (size_t)NTOK * DIM;
    const u16* qg = qkvb + ((size_t)b * NSEQ) * DIM + h * HD;
    const u16* kg = qg + MS;
    const u16* vg = qg + 2 * MS;

    for (int c = tid; c < 784; c += 256) {
        int row = c >> 2, ch = c & 3;
        gload_lds16(kg + (size_t)row * DIM + ch * 8, (char*)Ks + c * 16);
    }
    for (int i = tid; i < 448; i += 256) ((unsigned*)(Ks + 196 * 32))[i] = 0;
    for (int i = tid; i < 1568; i += 256) {
        int j = i >> 3, d0 = (i & 7) * 4;
        ushort4 vv = *(const ushort4*)(vg + (size_t)j * DIM + d0);
        VTs[(d0 + 0) * 232 + j] = vv.x;
        VTs[(d0 + 1) * 232 + j] = vv.y;
        VTs[(d0 + 2) * 232 + j] = vv.z;
        VTs[(d0 + 3) * 232 + j] = vv.w;
    }
    for (int i = tid; i < 1024; i += 256) {
        int d = i >> 5, j = 196 + (i & 31);
        VTs[d * 232 + j] = 0;
    }
    __syncthreads();

    const float scale = 0.17677669529663687f;   // 1/sqrt(32)
    char* psb = (char*)&Ps[wid][0];
    int pend = half ? 13 : 7;

    for (int p = half * 7 + wid; p < pend; p += 4) {
        int r0 = p * 16;
        int qrow = r0 + l16; if (qrow > 195) qrow = 195;
        bf16x8 qf = *(const bf16x8*)(qg + (size_t)qrow * DIM + kq * 8);

        f32x4 z4 = {0.f, 0.f, 0.f, 0.f};
        f32x4 s[14];
#pragma unroll
        for (int ct = 0; ct < 14; ++ct) {
            bf16x8 kf = *(const bf16x8*)&Ks[(ct * 16 + l16) * 32 + kq * 8];
            s[ct] = __builtin_amdgcn_mfma_f32_16x16x32_bf16(qf, kf, z4, 0, 0, 0);
        }
        bool v12 = (l16 < 4);   // tile 12 cols 192..207 valid iff l16<4
        float mx[4], sum[4], inv[4];
#pragma unroll
        for (int i = 0; i < 4; ++i) {
            float m = -1e30f;
#pragma unroll
            for (int ct = 0; ct < 12; ++ct) m = fmaxf(m, s[ct][i]);
            if (v12) m = fmaxf(m, s[12][i]);
            mx[i] = m * scale;
        }
#pragma unroll
        for (int off = 8; off; off >>= 1)
#pragma unroll
            for (int i = 0; i < 4; ++i) mx[i] = fmaxf(mx[i], __shfl_xor(mx[i], off));
#pragma unroll
        for (int i = 0; i < 4; ++i) sum[i] = 0.f;
#pragma unroll
        for (int ct = 0; ct < 14; ++ct)
#pragma unroll
            for (int i = 0; i < 4; ++i) {
                bool valid = (ct < 12) || (ct == 12 && v12);
                float e = valid ? __expf(s[ct][i] * scale - mx[i]) : 0.f;
                s[ct][i] = e;
                sum[i] += e;
            }
#pragma unroll
        for (int off = 8; off; off >>= 1)
#pragma unroll
            for (int i = 0; i < 4; ++i) sum[i] += __shfl_xor(sum[i], off);
#pragma unroll
        for (int i = 0; i < 4; ++i) inv[i] = 1.f / sum[i];

        f32x4 o0 = {0.f, 0.f, 0.f, 0.f}, o1 = {0.f, 0.f, 0.f, 0.f};
        // phase A: col tiles 0..7 -> Ps; PV k-tiles 0..3
#pragma unroll
        for (int ct = 0; ct < 8; ++ct)
#pragma unroll
            for (int i = 0; i < 4; ++i) {
                int rl = kq * 4 + i;
                int byte = rl * 256 + (((ct * 16 + l16) * 2) ^ ((rl & 7) << 4));
                *(u16*)(psb + byte) = f2bf(s[ct][i]);
            }
#pragma unroll
        for (int kt = 0; kt < 4; ++kt) {
            int K2 = (kt * 64 + kq * 16) ^ ((l16 & 7) << 4);
            bf16x8 pa = *(const bf16x8*)(psb + l16 * 256 + K2);
            bf16x8 va = *(const bf16x8*)&VTs[l16 * 232 + kt * 32 + kq * 8];
            bf16x8 vb = *(const bf16x8*)&VTs[(16 + l16) * 232 + kt * 32 + kq * 8];
            o0 = __builtin_amdgcn_mfma_f32_16x16x32_bf16(pa, va, o0, 0, 0, 0);
            o1 = __builtin_amdgcn_mfma_f32_16x16x32_bf16(pa, vb, o1, 0, 0, 0);
        }
        // phase B: col tiles 8..13 -> Ps (reused); PV k-tiles 4..6
#pragma unroll
        for (int ct = 8; ct < 14; ++ct)
#pragma unroll
            for (int i = 0; i < 4; ++i) {
                int rl = kq * 4 + i;
                int byte = rl * 256 + ((((ct - 8) * 16 + l16) * 2) ^ ((rl & 7) << 4));
                *(u16*)(psb + byte) = f2bf(s[ct][i]);
            }
#pragma unroll
        for (int kt = 4; kt < 7; ++kt) {
            int K2 = ((kt - 4) * 64 + kq * 16) ^ ((l16 & 7) << 4);
            bf16x8 pa = *(const bf16x8*)(psb + l16 * 256 + K2);
            bf16x8 va = *(const bf16x8*)&VTs[l16 * 232 + kt * 32 + kq * 8];
            bf16x8 vb = *(const bf16x8*)&VTs[(16 + l16) * 232 + kt * 32 + kq * 8];
            o0 = __builtin_amdgcn_mfma_f32_16x16x32_bf16(pa, va, o0, 0, 0, 0);
            o1 = __builtin_amdgcn_mfma_f32_16x16x32_bf16(pa, vb, o1, 0, 0, 0);
        }
#pragma unroll
        for (int i = 0; i < 4; ++i) {
            int row = r0 + kq * 4 + i;
            if (row < NSEQ) {
                size_t rb = ((size_t)b * NSEQ + row) * DIM + h * HD;
                ob[rb + l16] = f2bf(o0[i] * inv[i]);
                ob[rb + 16 + l16] = f2bf(o1[i] * inv[i]);
            }
        }
    }
}

// ---------------- final LayerNorm (bf16 in, fp32 out), one wave per token ----------------
__global__ __launch_bounds__(256) void ln_final(const u16* __restrict__ y,
                                                const float* __restrict__ gg,
                                                const float* __restrict__ bb,
                                                float* __restrict__ xout) {
    int t = blockIdx.x * 4 + (threadIdx.x >> 6);
    int lane = threadIdx.x & 63;
    size_t base = (size_t)t * DIM;
    int c0 = lane * 8;
    u16x8 yr = *(const u16x8*)(y + base + c0);
    float v[8];
    float s = 0.f, s2 = 0.f;
#pragma unroll
    for (int i = 0; i < 8; ++i) {
        v[i] = bf2f(yr[i]);
        s += v[i]; s2 += v[i] * v[i];
    }
#pragma unroll
    for (int off = 32; off; off >>= 1) { s += __shfl_xor(s, off); s2 += __shfl_xor(s2, off); }
    float m = s * (1.f / 512.f);
    float var = s2 * (1.f / 512.f) - m * m;
    float rs = rsqrtf(var + 1e-5f);
    float4 ga = *(const float4*)(gg + c0);
    float4 gc = *(const float4*)(gg + c0 + 4);
    float4 b0 = *(const float4*)(bb + c0);
    float4 b1 = *(const float4*)(bb + c0 + 4);
    float gs[8] = {ga.x, ga.y, ga.z, ga.w, gc.x, gc.y, gc.z, gc.w};
    float os[8] = {b0.x, b0.y, b0.z, b0.w, b1.x, b1.y, b1.z, b1.w};
    float o[8];
#pragma unroll
    for (int i = 0; i < 8; ++i) o[i] = (v[i] - m) * rs * gs[i] + os[i];
    float4 o0 = {o[0], o[1], o[2], o[3]};
    float4 o1 = {o[4], o[5], o[6], o[7]};
    *(float4*)(xout + base + c0) = o0;
    *(float4*)(xout + base + c0 + 4) = o1;
}

extern "C" void kernel_launch(void* const* d_in, const int* in_sizes, int n_in,
                              void* d_out, int out_size, void* d_ws, size_t ws_size,
                              hipStream_t stream) {
    const float* xenc = (const float*)d_in[0];
    const int*   idxr = (const int*)d_in[1];
    const float* mtok = (const float*)d_in[2];
    const float* pos  = (const float*)d_in[3];
    const float* Wq = (const float*)d_in[4];  const float* bq = (const float*)d_in[5];
    const float* Wk = (const float*)d_in[6];  const float* bk = (const float*)d_in[7];
    const float* Wv = (const float*)d_in[8];  const float* bv = (const float*)d_in[9];
    const float* Wo = (const float*)d_in[10]; const float* bo = (const float*)d_in[11];
    const float* ln1g = (const float*)d_in[12]; const float* ln1b = (const float*)d_in[13];
    const float* W1 = (const float*)d_in[14]; const float* b1 = (const float*)d_in[15];
    const float* W2 = (const float*)d_in[16]; const float* b2 = (const float*)d_in[17];
    const float* ln2g = (const float*)d_in[18]; const float* ln2b = (const float*)d_in[19];
    const float* lnfg = (const float*)d_in[20]; const float* lnfb = (const float*)d_in[21];

    // ---- workspace carve ----
    char* w = (char*)d_ws;
    u16* WTqkvo = (u16*)w; w += (size_t)4 * LAYERS * DIM * DIM * 2;     // bf16 W^T (q,k,v,o)
    u16* WT1    = (u16*)w; w += (size_t)LAYERS * DIM * FFD * 2;         // [8][2048][512]
    u16* WT2    = (u16*)w; w += (size_t)LAYERS * FFD * DIM * 2;         // [8][512][2048]
    float* bqkv = (float*)w; w += (size_t)3 * LAYERS * DIM * 4;         // [3][8][512]
    u16*   xb   = (u16*)w;  w += (size_t)NTOK * DIM * 2;                // bf16 residual stream
    u16*   qkvb = (u16*)w;  w += (size_t)3 * NTOK * DIM * 2;            // q,k,v bf16
    u16*   ob   = (u16*)w;  w += (size_t)NTOK * DIM * 2;                // attention out bf16
    u16*   hb   = (u16*)w;  w += (size_t)NTOK * FFD * 2;                // FF hidden bf16
    size_t need = (size_t)(w - (char*)d_ws);
    if (ws_size < need) return;

    // bf16 split-K partial slabs (2 x ND u16), aliased into qkvb (dead after attn / during FF2)
    u16* pp = qkvb;
    const long long ND = (long long)NTOK * DIM;

    const size_t WL = (size_t)DIM * DIM;

    // ---- weight prep ----
    transpose_w4<<<dim3(DIM / 32, DIM / 32, 4 * LAYERS), dim3(32, 8), 0, stream>>>(Wq, Wk, Wv, Wo, WTqkvo);
    transpose_w<<<dim3(FFD / 32, DIM / 32, LAYERS), dim3(32, 8), 0, stream>>>(W1, WT1, DIM, FFD);
    transpose_w<<<dim3(DIM / 32, FFD / 32, LAYERS), dim3(32, 8), 0, stream>>>(W2, WT2, FFD, DIM);
    pack3_bias<<<(LAYERS * DIM + 255) / 256, 256, 0, stream>>>(bq, bk, bv, bqkv, LAYERS * DIM);

    // ---- embed ----
    gather_pos<<<NTOK, 128, 0, stream>>>(xenc, idxr, mtok, pos, xb);

    for (int l = 0; l < LAYERS; ++l) {
        // QKV -> bf16 (z = weight slab 0..2)
        gemm4<3><<<dim3(4, 49, 3), 256, 0, stream>>>(
            xb, DIM, 0, WTqkvo + l * WL, DIM, (long long)LAYERS * WL,
            bqkv + l * DIM, (long long)LAYERS * DIM,
            qkvb, ND, DIM, DIM);
        // MFMA attention (2 blocks per (b,h))
        attn_mfma<<<BATCH * NHEAD * 2, 256, 0, stream>>>(qkvb, ob);
        // out projection, split-K=2 (z = K-slice), bf16 partials into pp
        gemm4<4><<<dim3(4, 49, 2), 256, 0, stream>>>(
            ob, DIM, 256, WTqkvo + 3 * (size_t)LAYERS * WL + l * WL, DIM, 256,
            nullptr, 0, pp, ND, DIM, 256);
        // reduce + bias + residual + LN1 (bf16 residual, in-place)
        red_ln<2><<<NTOK / 4, 256, 0, stream>>>(pp, ND, bo + l * DIM,
                                                ln1g + l * DIM, ln1b + l * DIM, xb);
        // FF1 (relu, bf16 out)
        gemm4<1><<<dim3(16, 49, 1), 256, 0, stream>>>(
            xb, DIM, 0, WT1 + (size_t)l * DIM * FFD, DIM, 0,
            b1 + l * FFD, 0, hb, 0, FFD, DIM);
        // FF2, split-K=2, bf16 partials into pp (qkvb dead)
        gemm4<4><<<dim3(4, 49, 2), 256, 0, stream>>>(
            hb, FFD, 1024, WT2 + (size_t)l * FFD * DIM, FFD, 1024,
            nullptr, 0, pp, ND, DIM, 1024);
        // reduce + bias + residual + LN2 (bf16 residual, in-place)
        red_ln<2><<<NTOK / 4, 256, 0, stream>>>(pp, ND, b2 + l * DIM,
                                                ln2g + l * DIM, ln2b + l * DIM, xb);
    }
    // final LN (bf16 in) -> d_out (fp32)
    ln_final<<<NTOK / 4, 256, 0, stream>>>(xb, lnfg, lnfb, (float*)d_out);
}

// Round 18
// 908.297 us; speedup vs baseline: 1.0637x; 1.0054x over previous
//
#include <hip/hip_runtime.h>

#define LAYERS 8
#define DIM 512
#define FFD 2048
#define NTOK 6272   // 32 * 196
#define NSEQ 196
#define BATCH 32
#define NHEAD 16
#define HD 32
#define NP 224      // padded seq for attention tiles

typedef unsigned short u16;
typedef __bf16 bf16x8 __attribute__((ext_vector_type(8)));
typedef float f32x4 __attribute__((ext_vector_type(4)));
typedef unsigned short u16x8 __attribute__((ext_vector_type(8)));

__device__ __forceinline__ u16 f2bf(float f) {
    unsigned u = __float_as_uint(f);
    u += 0x7FFF + ((u >> 16) & 1);   // round-to-nearest-even
    return (u16)(u >> 16);
}
__device__ __forceinline__ float bf2f(u16 u) {
    return __uint_as_float((unsigned)u << 16);
}

typedef __attribute__((address_space(1))) void gvoid_t;
typedef __attribute__((address_space(3))) void lvoid_t;
__device__ __forceinline__ void gload_lds16(const void* g, void* l) {
    __builtin_amdgcn_global_load_lds((gvoid_t*)g, (lvoid_t*)l, 16, 0, 0);
}

// ---------------- weight transpose + bf16 convert ----------------
// 4-in-1 for the DxD weights: z = sel*LAYERS + layer, sel in {q,k,v,o}
__global__ __launch_bounds__(256) void transpose_w4(const float* __restrict__ Wq,
                                                    const float* __restrict__ Wk,
                                                    const float* __restrict__ Wv,
                                                    const float* __restrict__ Wo,
                                                    u16* __restrict__ out) {
    __shared__ float t[32][33];
    int z = blockIdx.z;
    int sel = z >> 3, l = z & 7;
    const float* in = (sel == 0) ? Wq : (sel == 1) ? Wk : (sel == 2) ? Wv : Wo;
    size_t ibase = (size_t)l * DIM * DIM;
    size_t obase = (size_t)z * DIM * DIM;
    int n0 = blockIdx.x * 32, k0 = blockIdx.y * 32;
    int tx = threadIdx.x, ty = threadIdx.y;
#pragma unroll
    for (int i = 0; i < 4; ++i)
        t[ty + i * 8][tx] = in[ibase + (size_t)(k0 + ty + i * 8) * DIM + n0 + tx];
    __syncthreads();
#pragma unroll
    for (int i = 0; i < 4; ++i)
        out[obase + (size_t)(n0 + ty + i * 8) * DIM + k0 + tx] = f2bf(t[tx][ty + i * 8]);
}

__global__ __launch_bounds__(256) void transpose_w(const float* __restrict__ in,
                                                   u16* __restrict__ out, int K, int N) {
    __shared__ float t[32][33];
    size_t base = (size_t)blockIdx.z * K * N;
    int n0 = blockIdx.x * 32, k0 = blockIdx.y * 32;
    int tx = threadIdx.x, ty = threadIdx.y;
#pragma unroll
    for (int i = 0; i < 4; ++i)
        t[ty + i * 8][tx] = in[base + (size_t)(k0 + ty + i * 8) * N + n0 + tx];
    __syncthreads();
#pragma unroll
    for (int i = 0; i < 4; ++i)
        out[base + (size_t)(n0 + ty + i * 8) * K + k0 + tx] = f2bf(t[tx][ty + i * 8]);
}

__global__ void pack3_bias(const float* __restrict__ a, const float* __restrict__ b,
                           const float* __restrict__ c, float* __restrict__ o, int n) {
    int i = blockIdx.x * 256 + threadIdx.x;
    if (i < n) { o[i] = a[i]; o[n + i] = b[i]; o[2 * n + i] = c[i]; }
}

// ---------------- gather/unshuffle + pos_emb (bf16 residual stream only) ----------------
__global__ __launch_bounds__(128) void gather_pos(const float* __restrict__ xenc,
                                                  const int* __restrict__ idx,
                                                  const float* __restrict__ mtok,
                                                  const float* __restrict__ pos,
                                                  u16* __restrict__ xb) {
    int token = blockIdx.x;
    int b = token / NSEQ, t = token - b * NSEQ;
    int id = idx[token];
    const float* src = (id < 49) ? (xenc + ((size_t)b * 50 + id + 1) * DIM) : mtok;
    int d = threadIdx.x * 4;
    float4 s = *(const float4*)(src + d);
    float4 p = *(const float4*)(pos + (size_t)t * DIM + d);
    ushort4 rb;
    rb.x = f2bf(s.x + p.x); rb.y = f2bf(s.y + p.y);
    rb.z = f2bf(s.z + p.z); rb.w = f2bf(s.w + p.w);
    *(ushort4*)(xb + (size_t)token * DIM + d) = rb;
}

// ---------------- 4-wave 128x128 bf16 MFMA GEMM, BK=64, dbuf + counted vmcnt ----------------
// B^T input (Wt[N][K]); grid.z = slab (weight slab or K-slice)
// EPI 1: relu(A@B+bias)->bf16   EPI 3: A@B+bias->bf16   EPI 4: A@B->bf16 partial
// XOR swizzle ((row&7)<<4) via inverse-swizzled GLOBAL source offset (LDS dest
// linear, required by global_load_lds) + swizzled fragment reads.
// Pipeline (T3/T4): STAGE(next) then s_waitcnt vmcnt(8) — waits only for the
// CURRENT tile's 8 loads, never draining the just-issued prefetch.
// B stays LDS-staged: rounds 12/13 proved direct global->VGPR B either exposes
// L2 latency (r12) or thrashes cache (r13, FETCH 26->67MB).
// Epilogue: C bounced through LDS -> 8x u16x8 coalesced stores per thread.
// Cross-thread LDS exchange REQUIRES __syncthreads (round-10 race).
template<int EPI>
__global__ __launch_bounds__(256) void gemm4(
    const u16* __restrict__ A, int lda, long long zsA,
    const u16* __restrict__ Bt, int ldb, long long zsB,
    const float* __restrict__ bias, long long zsBias,
    u16* __restrict__ outB, long long zsOut,
    int N, int K) {
    __shared__ u16 smem[32768];        // 64KB: As dbuf [0..16383], Bs dbuf [16384..32767]
    int tid = threadIdx.x;
    int lane = tid & 63, wid = tid >> 6;
    int z = blockIdx.z;
    const u16* Az = A + (size_t)z * zsA;
    const u16* Bz = Bt + (size_t)z * zsB;
    int m0 = blockIdx.y * 128, n0 = blockIdx.x * 128;
    int l16 = lane & 15, kq = lane >> 4;
    int wm = (wid >> 1) * 64, wn = (wid & 1) * 64;

    f32x4 acc[4][4];
    f32x4 zero = {0.f, 0.f, 0.f, 0.f};
#pragma unroll
    for (int a = 0; a < 4; ++a)
#pragma unroll
        for (int b = 0; b < 4; ++b) acc[a][b] = zero;

#define STAGE(buf, kk)                                                             \
    {                                                                              \
        u16* asb_ = smem + (buf) * 8192;                                           \
        u16* bsb_ = smem + 16384 + (buf) * 8192;                                   \
        _Pragma("unroll")                                                          \
        for (int i_ = 0; i_ < 4; ++i_) {                                           \
            int c_ = i_ * 256 + tid;               /* 16B chunk id 0..1023 */      \
            int row_ = c_ >> 3;                    /* 128B (64 bf16) rows */       \
            int kof_ = ((c_ & 7) * 16) ^ ((row_ & 7) << 4);                        \
            gload_lds16((const char*)Az + ((size_t)(m0 + row_) * lda + (kk)) * 2 + kof_, \
                        (char*)asb_ + (size_t)c_ * 16);                            \
            gload_lds16((const char*)Bz + ((size_t)(n0 + row_) * ldb + (kk)) * 2 + kof_, \
                        (char*)bsb_ + (size_t)c_ * 16);                            \
        }                                                                          \
    }

    int nk = K >> 6;
    STAGE(0, 0);                       // 8 vmem ops in flight (tile 0)
    for (int kt = 0; kt < nk; ++kt) {
        int cur = kt & 1;
        if (kt + 1 < nk) {
            STAGE(cur ^ 1, (kt + 1) << 6);                     // +8 (tile kt+1)
            asm volatile("s_waitcnt vmcnt(8)" ::: "memory");   // tile kt landed
        } else {
            asm volatile("s_waitcnt vmcnt(0)" ::: "memory");   // final drain
        }
        __builtin_amdgcn_s_barrier();
        const char* Ac = (const char*)(smem + cur * 8192);
        const char* Bc = (const char*)(smem + 16384 + cur * 8192);
#pragma unroll
        for (int kh = 0; kh < 2; ++kh) {
            bf16x8 af[4], bfr[4];
#pragma unroll
            for (int mr = 0; mr < 4; ++mr) {
                int row = wm + mr * 16 + l16;
                int cb = (kh * 64 + kq * 16) ^ ((row & 7) << 4);
                af[mr] = *(const bf16x8*)(Ac + row * 128 + cb);
            }
#pragma unroll
            for (int nc = 0; nc < 4; ++nc) {
                int row = wn + nc * 16 + l16;
                int cb = (kh * 64 + kq * 16) ^ ((row & 7) << 4);
                bfr[nc] = *(const bf16x8*)(Bc + row * 128 + cb);
            }
#pragma unroll
            for (int mr = 0; mr < 4; ++mr)
#pragma unroll
                for (int nc = 0; nc < 4; ++nc)
                    acc[mr][nc] = __builtin_amdgcn_mfma_f32_16x16x32_bf16(af[mr], bfr[nc],
                                                                          acc[mr][nc], 0, 0, 0);
        }
        __builtin_amdgcn_s_barrier();  // all reads of buf cur done before it is re-staged
    }
#undef STAGE

    // ---- epilogue: bounce C tile through LDS (dead after K-loop) ----
    __syncthreads();                   // full drain: safe to repurpose smem
    const float* biasz = (EPI != 4) ? bias + (size_t)z * zsBias : nullptr;
    const int CLD = 136;               // padded u16 row stride (272B)
    u16* Cs = smem;                    // 128*136 = 17408 u16 <= 32768
#pragma unroll
    for (int mr = 0; mr < 4; ++mr)
#pragma unroll
        for (int nc = 0; nc < 4; ++nc)
#pragma unroll
            for (int i = 0; i < 4; ++i) {
                int rl = wm + mr * 16 + kq * 4 + i;   // row = (lane>>4)*4 + reg
                int cl = wn + nc * 16 + l16;          // col = lane&15
                float v = acc[mr][nc][i];
                if (EPI == 1) { v += biasz[n0 + cl]; v = v > 0.f ? v : 0.f; }
                else if (EPI == 3) { v += biasz[n0 + cl]; }
                Cs[rl * CLD + cl] = f2bf(v);
            }
    __syncthreads();                   // lgkmcnt(0) drain + barrier: writes visible
#pragma unroll
    for (int k = 0; k < 8; ++k) {
        int g = k * 256 + tid;                        // 2048 chunks of 16B
        int r = g >> 4, ch = g & 15;
        u16x8 val = *(const u16x8*)&Cs[r * CLD + ch * 8];
        *(u16x8*)&outB[(size_t)z * zsOut + (size_t)(m0 + r) * N + n0 + ch * 8] = val;
    }
}

// ---------------- fused split-K reduce (NS bf16 partials) + bias + bf16 residual + LN ----------------
// FINAL=0: write LN result to xb (bf16, in-place residual stream).
// FINAL=1: additionally apply the decoder-final LayerNorm (lnf) to the LN2
//          output IN REGISTERS (fp32, more accurate than the old xb round-trip)
//          and write fp32 to outF. No xb write (stream dead after).
template<int NS, int FINAL>
__global__ __launch_bounds__(256) void red_ln(const u16* __restrict__ p0, long long ps,
                                              const float* __restrict__ bias,
                                              const float* __restrict__ gg,
                                              const float* __restrict__ bb,
                                              u16* __restrict__ xb,
                                              const float* __restrict__ fg,
                                              const float* __restrict__ fb,
                                              float* __restrict__ outF) {
    int t = blockIdx.x * 4 + (threadIdx.x >> 6);
    int lane = threadIdx.x & 63;
    size_t base = (size_t)t * DIM;
    int c0 = lane * 8;
    float v[8];
    {
        u16x8 pa = *(const u16x8*)(p0 + base + c0);
#pragma unroll
        for (int i = 0; i < 8; ++i) v[i] = bf2f(pa[i]);
    }
#pragma unroll
    for (int s2i = 1; s2i < NS; ++s2i) {
        u16x8 pb = *(const u16x8*)(p0 + (size_t)s2i * ps + base + c0);
#pragma unroll
        for (int i = 0; i < 8; ++i) v[i] += bf2f(pb[i]);
    }
    u16x8 xr = *(const u16x8*)(xb + base + c0);
    float4 ba = *(const float4*)(bias + c0);
    float4 bc = *(const float4*)(bias + c0 + 4);
    float bs[8] = {ba.x, ba.y, ba.z, ba.w, bc.x, bc.y, bc.z, bc.w};
    float s = 0.f, s2 = 0.f;
#pragma unroll
    for (int i = 0; i < 8; ++i) {
        v[i] += bs[i] + bf2f(xr[i]);
        s += v[i]; s2 += v[i] * v[i];
    }
#pragma unroll
    for (int off = 32; off; off >>= 1) { s += __shfl_xor(s, off); s2 += __shfl_xor(s2, off); }
    float m = s * (1.f / 512.f);
    float var = s2 * (1.f / 512.f) - m * m;
    float rs = rsqrtf(var + 1e-5f);
    float4 ga = *(const float4*)(gg + c0);
    float4 gc = *(const float4*)(gg + c0 + 4);
    float4 b0 = *(const float4*)(bb + c0);
    float4 b1 = *(const float4*)(bb + c0 + 4);
    float gs[8] = {ga.x, ga.y, ga.z, ga.w, gc.x, gc.y, gc.z, gc.w};
    float os[8] = {b0.x, b0.y, b0.z, b0.w, b1.x, b1.y, b1.z, b1.w};
    float o[8];
#pragma unroll
    for (int i = 0; i < 8; ++i)
        o[i] = (v[i] - m) * rs * gs[i] + os[i];
    if (!FINAL) {
        u16x8 ob16;
#pragma unroll
        for (int i = 0; i < 8; ++i) ob16[i] = f2bf(o[i]);
        *(u16x8*)(xb + base + c0) = ob16;
    } else {
        // decoder-final LN over the fp32 LN2 output (in registers)
        float fs = 0.f, fs2 = 0.f;
#pragma unroll
        for (int i = 0; i < 8; ++i) { fs += o[i]; fs2 += o[i] * o[i]; }
#pragma unroll
        for (int off = 32; off; off >>= 1) { fs += __shfl_xor(fs, off); fs2 += __shfl_xor(fs2, off); }
        float fm = fs * (1.f / 512.f);
        float frs = rsqrtf(fs2 * (1.f / 512.f) - fm * fm + 1e-5f);
        float4 fga = *(const float4*)(fg + c0);
        float4 fgc = *(const float4*)(fg + c0 + 4);
        float4 fb0 = *(const float4*)(fb + c0);
        float4 fb1 = *(const float4*)(fb + c0 + 4);
        float fgs[8] = {fga.x, fga.y, fga.z, fga.w, fgc.x, fgc.y, fgc.z, fgc.w};
        float fos[8] = {fb0.x, fb0.y, fb0.z, fb0.w, fb1.x, fb1.y, fb1.z, fb1.w};
        float r[8];
#pragma unroll
        for (int i = 0; i < 8; ++i) r[i] = (o[i] - fm) * frs * fgs[i] + fos[i];
        float4 r0 = {r[0], r[1], r[2], r[3]};
        float4 r1 = {r[4], r[5], r[6], r[7]};
        *(float4*)(outF + base + c0) = r0;
        *(float4*)(outF + base + c0 + 4) = r1;
    }
}

// ---------------- MFMA flash attention, 2 blocks per (b,h), 4 waves each ----------------
__global__ __launch_bounds__(256) void attn_mfma(const u16* __restrict__ qkvb,
                                                 u16* __restrict__ ob) {
    __shared__ u16 Ks[NP * 32];            // [224][32] row-major
    __shared__ u16 VTs[32 * 232];          // [32][232] V transposed
    __shared__ u16 Ps[4][16 * 128];        // per-wave P panel, 256B rows
    int bh = blockIdx.x >> 1, half = blockIdx.x & 1;
    int b = bh >> 4, h = bh & 15;
    int tid = threadIdx.x, lane = tid & 63, wid = tid >> 6;
    int l16 = lane & 15, kq = lane >> 4;
    const size_t MS = (size_t)NTOK * DIM;
    const u16* qg = qkvb + ((size_t)b * NSEQ) * DIM + h * HD;
    const u16* kg = qg + MS;
    const u16* vg = qg + 2 * MS;

    for (int c = tid; c < 784; c += 256) {
        int row = c >> 2, ch = c & 3;
        gload_lds16(kg + (size_t)row * DIM + ch * 8, (char*)Ks + c * 16);
    }
    for (int i = tid; i < 448; i += 256) ((unsigned*)(Ks + 196 * 32))[i] = 0;
    for (int i = tid; i < 1568; i += 256) {
        int j = i >> 3, d0 = (i & 7) * 4;
        ushort4 vv = *(const ushort4*)(vg + (size_t)j * DIM + d0);
        VTs[(d0 + 0) * 232 + j] = vv.x;
        VTs[(d0 + 1) * 232 + j] = vv.y;
        VTs[(d0 + 2) * 232 + j] = vv.z;
        VTs[(d0 + 3) * 232 + j] = vv.w;
    }
    for (int i = tid; i < 1024; i += 256) {
        int d = i >> 5, j = 196 + (i & 31);
        VTs[d * 232 + j] = 0;
    }
    __syncthreads();

    const float scale = 0.17677669529663687f;   // 1/sqrt(32)
    char* psb = (char*)&Ps[wid][0];
    int pend = half ? 13 : 7;

    for (int p = half * 7 + wid; p < pend; p += 4) {
        int r0 = p * 16;
        int qrow = r0 + l16; if (qrow > 195) qrow = 195;
        bf16x8 qf = *(const bf16x8*)(qg + (size_t)qrow * DIM + kq * 8);

        f32x4 z4 = {0.f, 0.f, 0.f, 0.f};
        f32x4 s[14];
#pragma unroll
        for (int ct = 0; ct < 14; ++ct) {
            bf16x8 kf = *(const bf16x8*)&Ks[(ct * 16 + l16) * 32 + kq * 8];
            s[ct] = __builtin_amdgcn_mfma_f32_16x16x32_bf16(qf, kf, z4, 0, 0, 0);
        }
        bool v12 = (l16 < 4);   // tile 12 cols 192..207 valid iff l16<4
        float mx[4], sum[4], inv[4];
#pragma unroll
        for (int i = 0; i < 4; ++i) {
            float m = -1e30f;
#pragma unroll
            for (int ct = 0; ct < 12; ++ct) m = fmaxf(m, s[ct][i]);
            if (v12) m = fmaxf(m, s[12][i]);
            mx[i] = m * scale;
        }
#pragma unroll
        for (int off = 8; off; off >>= 1)
#pragma unroll
            for (int i = 0; i < 4; ++i) mx[i] = fmaxf(mx[i], __shfl_xor(mx[i], off));
#pragma unroll
        for (int i = 0; i < 4; ++i) sum[i] = 0.f;
#pragma unroll
        for (int ct = 0; ct < 14; ++ct)
#pragma unroll
            for (int i = 0; i < 4; ++i) {
                bool valid = (ct < 12) || (ct == 12 && v12);
                float e = valid ? __expf(s[ct][i] * scale - mx[i]) : 0.f;
                s[ct][i] = e;
                sum[i] += e;
            }
#pragma unroll
        for (int off = 8; off; off >>= 1)
#pragma unroll
            for (int i = 0; i < 4; ++i) sum[i] += __shfl_xor(sum[i], off);
#pragma unroll
        for (int i = 0; i < 4; ++i) inv[i] = 1.f / sum[i];

        f32x4 o0 = {0.f, 0.f, 0.f, 0.f}, o1 = {0.f, 0.f, 0.f, 0.f};
        // phase A: col tiles 0..7 -> Ps; PV k-tiles 0..3
#pragma unroll
        for (int ct = 0; ct < 8; ++ct)
#pragma unroll
            for (int i = 0; i < 4; ++i) {
                int rl = kq * 4 + i;
                int byte = rl * 256 + (((ct * 16 + l16) * 2) ^ ((rl & 7) << 4));
                *(u16*)(psb + byte) = f2bf(s[ct][i]);
            }
#pragma unroll
        for (int kt = 0; kt < 4; ++kt) {
            int K2 = (kt * 64 + kq * 16) ^ ((l16 & 7) << 4);
            bf16x8 pa = *(const bf16x8*)(psb + l16 * 256 + K2);
            bf16x8 va = *(const bf16x8*)&VTs[l16 * 232 + kt * 32 + kq * 8];
            bf16x8 vb = *(const bf16x8*)&VTs[(16 + l16) * 232 + kt * 32 + kq * 8];
            o0 = __builtin_amdgcn_mfma_f32_16x16x32_bf16(pa, va, o0, 0, 0, 0);
            o1 = __builtin_amdgcn_mfma_f32_16x16x32_bf16(pa, vb, o1, 0, 0, 0);
        }
        // phase B: col tiles 8..13 -> Ps (reused); PV k-tiles 4..6
#pragma unroll
        for (int ct = 8; ct < 14; ++ct)
#pragma unroll
            for (int i = 0; i < 4; ++i) {
                int rl = kq * 4 + i;
                int byte = rl * 256 + ((((ct - 8) * 16 + l16) * 2) ^ ((rl & 7) << 4));
                *(u16*)(psb + byte) = f2bf(s[ct][i]);
            }
#pragma unroll
        for (int kt = 4; kt < 7; ++kt) {
            int K2 = ((kt - 4) * 64 + kq * 16) ^ ((l16 & 7) << 4);
            bf16x8 pa = *(const bf16x8*)(psb + l16 * 256 + K2);
            bf16x8 va = *(const bf16x8*)&VTs[l16 * 232 + kt * 32 + kq * 8];
            bf16x8 vb = *(const bf16x8*)&VTs[(16 + l16) * 232 + kt * 32 + kq * 8];
            o0 = __builtin_amdgcn_mfma_f32_16x16x32_bf16(pa, va, o0, 0, 0, 0);
            o1 = __builtin_amdgcn_mfma_f32_16x16x32_bf16(pa, vb, o1, 0, 0, 0);
        }
#pragma unroll
        for (int i = 0; i < 4; ++i) {
            int row = r0 + kq * 4 + i;
            if (row < NSEQ) {
                size_t rb = ((size_t)b * NSEQ + row) * DIM + h * HD;
                ob[rb + l16] = f2bf(o0[i] * inv[i]);
                ob[rb + 16 + l16] = f2bf(o1[i] * inv[i]);
            }
        }
    }
}

extern "C" void kernel_launch(void* const* d_in, const int* in_sizes, int n_in,
                              void* d_out, int out_size, void* d_ws, size_t ws_size,
                              hipStream_t stream) {
    const float* xenc = (const float*)d_in[0];
    const int*   idxr = (const int*)d_in[1];
    const float* mtok = (const float*)d_in[2];
    const float* pos  = (const float*)d_in[3];
    const float* Wq = (const float*)d_in[4];  const float* bq = (const float*)d_in[5];
    const float* Wk = (const float*)d_in[6];  const float* bk = (const float*)d_in[7];
    const float* Wv = (const float*)d_in[8];  const float* bv = (const float*)d_in[9];
    const float* Wo = (const float*)d_in[10]; const float* bo = (const float*)d_in[11];
    const float* ln1g = (const float*)d_in[12]; const float* ln1b = (const float*)d_in[13];
    const float* W1 = (const float*)d_in[14]; const float* b1 = (const float*)d_in[15];
    const float* W2 = (const float*)d_in[16]; const float* b2 = (const float*)d_in[17];
    const float* ln2g = (const float*)d_in[18]; const float* ln2b = (const float*)d_in[19];
    const float* lnfg = (const float*)d_in[20]; const float* lnfb = (const float*)d_in[21];

    // ---- workspace carve ----
    char* w = (char*)d_ws;
    u16* WTqkvo = (u16*)w; w += (size_t)4 * LAYERS * DIM * DIM * 2;     // bf16 W^T (q,k,v,o)
    u16* WT1    = (u16*)w; w += (size_t)LAYERS * DIM * FFD * 2;         // [8][2048][512]
    u16* WT2    = (u16*)w; w += (size_t)LAYERS * FFD * DIM * 2;         // [8][512][2048]
    float* bqkv = (float*)w; w += (size_t)3 * LAYERS * DIM * 4;         // [3][8][512]
    u16*   xb   = (u16*)w;  w += (size_t)NTOK * DIM * 2;                // bf16 residual stream
    u16*   qkvb = (u16*)w;  w += (size_t)3 * NTOK * DIM * 2;            // q,k,v bf16
    u16*   ob   = (u16*)w;  w += (size_t)NTOK * DIM * 2;                // attention out bf16
    u16*   hb   = (u16*)w;  w += (size_t)NTOK * FFD * 2;                // FF hidden bf16
    size_t need = (size_t)(w - (char*)d_ws);
    if (ws_size < need) return;

    // bf16 split-K partial slabs (2 x ND u16), aliased into qkvb (dead after attn / during FF2)
    u16* pp = qkvb;
    const long long ND = (long long)NTOK * DIM;

    const size_t WL = (size_t)DIM * DIM;

    // ---- weight prep ----
    transpose_w4<<<dim3(DIM / 32, DIM / 32, 4 * LAYERS), dim3(32, 8), 0, stream>>>(Wq, Wk, Wv, Wo, WTqkvo);
    transpose_w<<<dim3(FFD / 32, DIM / 32, LAYERS), dim3(32, 8), 0, stream>>>(W1, WT1, DIM, FFD);
    transpose_w<<<dim3(DIM / 32, FFD / 32, LAYERS), dim3(32, 8), 0, stream>>>(W2, WT2, FFD, DIM);
    pack3_bias<<<(LAYERS * DIM + 255) / 256, 256, 0, stream>>>(bq, bk, bv, bqkv, LAYERS * DIM);

    // ---- embed ----
    gather_pos<<<NTOK, 128, 0, stream>>>(xenc, idxr, mtok, pos, xb);

    for (int l = 0; l < LAYERS; ++l) {
        // QKV -> bf16 (z = weight slab 0..2)
        gemm4<3><<<dim3(4, 49, 3), 256, 0, stream>>>(
            xb, DIM, 0, WTqkvo + l * WL, DIM, (long long)LAYERS * WL,
            bqkv + l * DIM, (long long)LAYERS * DIM,
            qkvb, ND, DIM, DIM);
        // MFMA attention (2 blocks per (b,h))
        attn_mfma<<<BATCH * NHEAD * 2, 256, 0, stream>>>(qkvb, ob);
        // out projection, split-K=2 (z = K-slice), bf16 partials into pp
        gemm4<4><<<dim3(4, 49, 2), 256, 0, stream>>>(
            ob, DIM, 256, WTqkvo + 3 * (size_t)LAYERS * WL + l * WL, DIM, 256,
            nullptr, 0, pp, ND, DIM, 256);
        // reduce + bias + residual + LN1 (bf16 residual, in-place)
        red_ln<2, 0><<<NTOK / 4, 256, 0, stream>>>(pp, ND, bo + l * DIM,
                                                   ln1g + l * DIM, ln1b + l * DIM, xb,
                                                   nullptr, nullptr, nullptr);
        // FF1 (relu, bf16 out)
        gemm4<1><<<dim3(16, 49, 1), 256, 0, stream>>>(
            xb, DIM, 0, WT1 + (size_t)l * DIM * FFD, DIM, 0,
            b1 + l * FFD, 0, hb, 0, FFD, DIM);
        // FF2, split-K=2, bf16 partials into pp (qkvb dead)
        gemm4<4><<<dim3(4, 49, 2), 256, 0, stream>>>(
            hb, FFD, 1024, WT2 + (size_t)l * FFD * DIM, FFD, 1024,
            nullptr, 0, pp, ND, DIM, 1024);
        // reduce + bias + residual + LN2; last layer fuses the decoder-final LN -> d_out
        if (l < LAYERS - 1) {
            red_ln<2, 0><<<NTOK / 4, 256, 0, stream>>>(pp, ND, b2 + l * DIM,
                                                       ln2g + l * DIM, ln2b + l * DIM, xb,
                                                       nullptr, nullptr, nullptr);
        } else {
            red_ln<2, 1><<<NTOK / 4, 256, 0, stream>>>(pp, ND, b2 + l * DIM,
                                                       ln2g + l * DIM, ln2b + l * DIM, xb,
                                                       lnfg, lnfb, (float*)d_out);
        }
    }
}